// Round 2
// baseline (1171.493 us; speedup 1.0000x reference)
//
#include <hip/hip_runtime.h>
#include <hip/hip_bf16.h>

#define DIM 128
#define LDS_STRIDE 136  // 128 + 8 bf16 pad: 16B-aligned, rows 0..15 spread across banks

typedef __attribute__((ext_vector_type(8))) __bf16 bf16x8;
typedef __attribute__((ext_vector_type(4))) __bf16 bf16x4;
typedef __attribute__((ext_vector_type(2))) __bf16 bf16x2;
typedef __attribute__((ext_vector_type(4))) float f32x4;

// ---------------------------------------------------------------------------
// P[j][n][c] = sum_k src[n][k] * W[j*128+k][c], output bf16.
// One block = 128-node tile, 4 waves, mfma_f32_16x16x32_bf16.
// A frag: row=lane&15, k=(lane>>4)*8+i ; B frag: col=lane&15, k=(lane>>4)*8+i
// D frag: col=lane&15, row=(lane>>4)*4+r   (m89-verified layout)
// ---------------------------------------------------------------------------
__global__ __launch_bounds__(256) void pre_gemm(const float* __restrict__ src,
                                                const float* __restrict__ W,
                                                __bf16* __restrict__ dst,
                                                int nj, int N)
{
    __shared__ __bf16 sA[128][LDS_STRIDE];
    __shared__ __bf16 sB[128][LDS_STRIDE];  // transposed: sB[c][k]
    const int tid = threadIdx.x;
    const int node0 = blockIdx.x * 128;

    for (int it = 0; it < 16; ++it) {
        int idx = tid + it * 256;
        int row = idx >> 5;
        int c4  = (idx & 31) << 2;
        float4 v = make_float4(0.f, 0.f, 0.f, 0.f);
        int grow = node0 + row;
        if (grow < N) v = *(const float4*)(src + (size_t)grow * DIM + c4);
        bf16x4 b;
        b[0] = (__bf16)v.x; b[1] = (__bf16)v.y; b[2] = (__bf16)v.z; b[3] = (__bf16)v.w;
        *(bf16x4*)&sA[row][c4] = b;
    }

    const int wave = tid >> 6, lane = tid & 63;
    const int rbase = wave * 32;
    const int lrow = lane & 15;
    const int lk   = (lane >> 4) * 8;

    for (int j = 0; j < nj; ++j) {
        __syncthreads();  // sA ready (j=0) / previous iter's MFMA done with sB
        const float* Wj = W + (size_t)j * DIM * DIM;
        for (int it = 0; it < 16; ++it) {
            int idx = tid + it * 256;
            int k  = idx >> 5;
            int c4 = (idx & 31) << 2;
            float4 v = *(const float4*)(Wj + k * DIM + c4);
            sB[c4 + 0][k] = (__bf16)v.x;
            sB[c4 + 1][k] = (__bf16)v.y;
            sB[c4 + 2][k] = (__bf16)v.z;
            sB[c4 + 3][k] = (__bf16)v.w;
        }
        __syncthreads();

        f32x4 acc[2][8];
        #pragma unroll
        for (int rt = 0; rt < 2; ++rt)
            #pragma unroll
            for (int ct = 0; ct < 8; ++ct) acc[rt][ct] = (f32x4){0.f, 0.f, 0.f, 0.f};

        #pragma unroll
        for (int ks = 0; ks < 4; ++ks) {
            int k0 = ks * 32 + lk;
            bf16x8 a0 = *(const bf16x8*)&sA[rbase + lrow][k0];
            bf16x8 a1 = *(const bf16x8*)&sA[rbase + 16 + lrow][k0];
            #pragma unroll
            for (int ct = 0; ct < 8; ++ct) {
                bf16x8 b = *(const bf16x8*)&sB[ct * 16 + lrow][k0];
                acc[0][ct] = __builtin_amdgcn_mfma_f32_16x16x32_bf16(a0, b, acc[0][ct], 0, 0, 0);
                acc[1][ct] = __builtin_amdgcn_mfma_f32_16x16x32_bf16(a1, b, acc[1][ct], 0, 0, 0);
            }
        }

        __bf16* dj = dst + (size_t)j * N * DIM;
        #pragma unroll
        for (int rt = 0; rt < 2; ++rt) {
            int row0 = node0 + rbase + rt * 16 + (lane >> 4) * 4;
            #pragma unroll
            for (int r = 0; r < 4; ++r) {
                int row = row0 + r;
                if (row < N) {
                    #pragma unroll
                    for (int ct = 0; ct < 8; ++ct)
                        dj[(size_t)row * DIM + ct * 16 + lrow] = (__bf16)acc[rt][ct][r];
                }
            }
        }
    }
}

__device__ __forceinline__ float silu(float x) { return x / (1.f + __expf(-x)); }

// ---------------------------------------------------------------------------
// Angle edges: one wave per edge, 2 channels/lane.
// m = silu(P0[i0]+P1[i1]+P2[i2]+v*wl+b); agg[i1] += m (atomic f32)
// ---------------------------------------------------------------------------
__global__ __launch_bounds__(256) void edge_agg3(const __bf16* __restrict__ P,
                                                 const int* __restrict__ idx,
                                                 const float* __restrict__ val,
                                                 const float* __restrict__ wlast,
                                                 const float* __restrict__ bias,
                                                 float* __restrict__ agg, int E, int N)
{
    int w = blockIdx.x * 4 + (threadIdx.x >> 6);
    if (w >= E) return;
    int lane = threadIdx.x & 63;
    const size_t NB = (size_t)N * DIM;
    int i0 = idx[3 * (size_t)w + 0];
    int i1 = idx[3 * (size_t)w + 1];
    int i2 = idx[3 * (size_t)w + 2];
    float v = val[w];
    int f = lane * 2;
    bf16x2 p0 = *(const bf16x2*)(P +          (size_t)i0 * DIM + f);
    bf16x2 p1 = *(const bf16x2*)(P + NB     + (size_t)i1 * DIM + f);
    bf16x2 p2 = *(const bf16x2*)(P + 2 * NB + (size_t)i2 * DIM + f);
    float2 wl = *(const float2*)(wlast + f);
    float2 bb = *(const float2*)(bias + f);
    float m0 = (float)p0[0] + (float)p1[0] + (float)p2[0] + v * wl.x + bb.x;
    float m1 = (float)p0[1] + (float)p1[1] + (float)p2[1] + v * wl.y + bb.y;
    m0 = silu(m0);
    m1 = silu(m1);
    atomicAdd(agg + (size_t)i1 * DIM + f,     m0);
    atomicAdd(agg + (size_t)i1 * DIM + f + 1, m1);
}

__global__ __launch_bounds__(256) void edge_agg4(const __bf16* __restrict__ P,
                                                 const int* __restrict__ idx,
                                                 const float* __restrict__ val,
                                                 const float* __restrict__ wlast,
                                                 const float* __restrict__ bias,
                                                 float* __restrict__ agg, int E, int N)
{
    int w = blockIdx.x * 4 + (threadIdx.x >> 6);
    if (w >= E) return;
    int lane = threadIdx.x & 63;
    const size_t NB = (size_t)N * DIM;
    int i0 = idx[4 * (size_t)w + 0];
    int i1 = idx[4 * (size_t)w + 1];
    int i2 = idx[4 * (size_t)w + 2];
    int i3 = idx[4 * (size_t)w + 3];
    float v = val[w];
    int f = lane * 2;
    bf16x2 p0 = *(const bf16x2*)(P +          (size_t)i0 * DIM + f);
    bf16x2 p1 = *(const bf16x2*)(P + NB     + (size_t)i1 * DIM + f);
    bf16x2 p2 = *(const bf16x2*)(P + 2 * NB + (size_t)i2 * DIM + f);
    bf16x2 p3 = *(const bf16x2*)(P + 3 * NB + (size_t)i3 * DIM + f);
    float2 wl = *(const float2*)(wlast + f);
    float2 bb = *(const float2*)(bias + f);
    float m0 = (float)p0[0] + (float)p1[0] + (float)p2[0] + (float)p3[0] + v * wl.x + bb.x;
    float m1 = (float)p0[1] + (float)p1[1] + (float)p2[1] + (float)p3[1] + v * wl.y + bb.y;
    m0 = silu(m0);
    m1 = silu(m1);
    atomicAdd(agg + (size_t)i1 * DIM + f,     m0);
    atomicAdd(agg + (size_t)i1 * DIM + f + 1, m1);
}

// ---------------------------------------------------------------------------
// out[row][col] = resid[row][col] + (bh?bh[col]:0) + sum_s srcs[s]@W[s]
// nsrc in {1,2}. Stage2 uses resid==out (same-thread read-then-write: safe).
// ---------------------------------------------------------------------------
__global__ __launch_bounds__(256) void update_gemm(const float* __restrict__ src0,
                                                   const float* __restrict__ src1,
                                                   const float* __restrict__ Wh,
                                                   const float* __restrict__ bh,
                                                   const float* resid,
                                                   float* out, int nsrc, int N)
{
    __shared__ __bf16 sA[128][LDS_STRIDE];
    __shared__ __bf16 sB[128][LDS_STRIDE];
    const int tid = threadIdx.x;
    const int node0 = blockIdx.x * 128;
    const int wave = tid >> 6, lane = tid & 63;
    const int rbase = wave * 32;
    const int lrow = lane & 15;
    const int lk   = (lane >> 4) * 8;

    f32x4 acc[2][8];
    #pragma unroll
    for (int rt = 0; rt < 2; ++rt)
        #pragma unroll
        for (int ct = 0; ct < 8; ++ct) acc[rt][ct] = (f32x4){0.f, 0.f, 0.f, 0.f};

    const float* srcs[2] = {src0, src1};
    for (int s = 0; s < nsrc; ++s) {
        __syncthreads();
        const float* src = srcs[s];
        for (int it = 0; it < 16; ++it) {
            int idx = tid + it * 256;
            int row = idx >> 5;
            int c4  = (idx & 31) << 2;
            float4 v = make_float4(0.f, 0.f, 0.f, 0.f);
            int grow = node0 + row;
            if (grow < N) v = *(const float4*)(src + (size_t)grow * DIM + c4);
            bf16x4 b;
            b[0] = (__bf16)v.x; b[1] = (__bf16)v.y; b[2] = (__bf16)v.z; b[3] = (__bf16)v.w;
            *(bf16x4*)&sA[row][c4] = b;
        }
        const float* Ws = Wh + (size_t)s * DIM * DIM;
        for (int it = 0; it < 16; ++it) {
            int idx = tid + it * 256;
            int k  = idx >> 5;
            int c4 = (idx & 31) << 2;
            float4 v = *(const float4*)(Ws + k * DIM + c4);
            sB[c4 + 0][k] = (__bf16)v.x;
            sB[c4 + 1][k] = (__bf16)v.y;
            sB[c4 + 2][k] = (__bf16)v.z;
            sB[c4 + 3][k] = (__bf16)v.w;
        }
        __syncthreads();
        #pragma unroll
        for (int ks = 0; ks < 4; ++ks) {
            int k0 = ks * 32 + lk;
            bf16x8 a0 = *(const bf16x8*)&sA[rbase + lrow][k0];
            bf16x8 a1 = *(const bf16x8*)&sA[rbase + 16 + lrow][k0];
            #pragma unroll
            for (int ct = 0; ct < 8; ++ct) {
                bf16x8 b = *(const bf16x8*)&sB[ct * 16 + lrow][k0];
                acc[0][ct] = __builtin_amdgcn_mfma_f32_16x16x32_bf16(a0, b, acc[0][ct], 0, 0, 0);
                acc[1][ct] = __builtin_amdgcn_mfma_f32_16x16x32_bf16(a1, b, acc[1][ct], 0, 0, 0);
            }
        }
    }

    #pragma unroll
    for (int rt = 0; rt < 2; ++rt) {
        int row0 = node0 + rbase + rt * 16 + (lane >> 4) * 4;
        #pragma unroll
        for (int r = 0; r < 4; ++r) {
            int row = row0 + r;
            if (row < N) {
                #pragma unroll
                for (int ct = 0; ct < 8; ++ct) {
                    int col = ct * 16 + lrow;
                    float base = resid[(size_t)row * DIM + col] + (bh ? bh[col] : 0.f);
                    out[(size_t)row * DIM + col] = base + acc[rt][ct][r];
                }
            }
        }
    }
}

// ---------------------------------------------------------------------------
// ws layout (peak 153.6 MB):
//   [0, 102.4MB): P, up to 4 buffers of N*128 bf16
//   [102.4MB, 153.6MB): agg, one N*128 f32 buffer (reused by both paths)
// ---------------------------------------------------------------------------
extern "C" void kernel_launch(void* const* d_in, const int* in_sizes, int n_in,
                              void* d_out, int out_size, void* d_ws, size_t ws_size,
                              hipStream_t stream)
{
    const float* h     = (const float*)d_in[0];
    const int*   a_idx = (const int*)d_in[1];
    const float* a_val = (const float*)d_in[2];
    const int*   d_idx = (const int*)d_in[3];
    const float* d_val = (const float*)d_in[4];
    const float* W_a   = (const float*)d_in[5];
    const float* b_a   = (const float*)d_in[6];
    const float* W_d   = (const float*)d_in[7];
    const float* b_d   = (const float*)d_in[8];
    const float* W_h   = (const float*)d_in[9];
    const float* b_h   = (const float*)d_in[10];
    float* out = (float*)d_out;

    const int N  = in_sizes[0] / DIM;   // 100000
    const int EA = in_sizes[2];         // 500000
    const int ED = in_sizes[4];         // 500000
    const size_t NB = (size_t)N * DIM;

    const size_t need = 4 * NB * sizeof(__bf16) + NB * sizeof(float);
    if (ws_size < need) return;  // diagnostic: clean absmax failure => ws too small

    __bf16* P   = (__bf16*)d_ws;
    float*  agg = (float*)((char*)d_ws + 4 * NB * sizeof(__bf16));

    const int NT = (N + 127) / 128;

    // ---- angle path ----
    pre_gemm<<<NT, 256, 0, stream>>>(h, W_a, P, 3, N);
    hipMemsetAsync(agg, 0, NB * sizeof(float), stream);
    edge_agg3<<<(EA + 3) / 4, 256, 0, stream>>>(P, a_idx, a_val, W_a + 384 * DIM, b_a, agg, EA, N);

    // stage 1: out = h + b_h + h@Wh0 + agg_a@Wh1   (consumes agg)
    update_gemm<<<NT, 256, 0, stream>>>(h, agg, W_h, b_h, h, out, 2, N);

    // ---- dihedral path (reuses P and agg) ----
    pre_gemm<<<NT, 256, 0, stream>>>(h, W_d, P, 4, N);
    hipMemsetAsync(agg, 0, NB * sizeof(float), stream);
    edge_agg4<<<(ED + 3) / 4, 256, 0, stream>>>(P, d_idx, d_val, W_d + 512 * DIM, b_d, agg, ED, N);

    // stage 2: out += agg_d@Wh2   (in-place)
    update_gemm<<<NT, 256, 0, stream>>>(agg, nullptr, W_h + 2 * DIM * DIM, nullptr, out, out, 1, N);
}

// Round 3
// 630.424 us; speedup vs baseline: 1.8583x; 1.8583x over previous
//
#include <hip/hip_runtime.h>
#include <hip/hip_bf16.h>

#define DIM 128
#define LDS_STRIDE 136  // 128 + 8 bf16 pad: 16B-aligned, breaks bank aliasing

typedef __attribute__((ext_vector_type(8))) __bf16 bf16x8;
typedef __attribute__((ext_vector_type(4))) __bf16 bf16x4;
typedef __attribute__((ext_vector_type(2))) __bf16 bf16x2;
typedef __attribute__((ext_vector_type(4))) float f32x4;

// ---------------------------------------------------------------------------
// P[j][n][c] = sum_k src[n][k] * W[j*128+k][c], output bf16.
// One block = 128-node tile, 4 waves, mfma_f32_16x16x32_bf16.
// ---------------------------------------------------------------------------
__global__ __launch_bounds__(256) void pre_gemm(const float* __restrict__ src,
                                                const float* __restrict__ W,
                                                __bf16* __restrict__ dst,
                                                int nj, int N)
{
    __shared__ __bf16 sA[128][LDS_STRIDE];
    __shared__ __bf16 sB[128][LDS_STRIDE];  // transposed: sB[c][k]
    const int tid = threadIdx.x;
    const int node0 = blockIdx.x * 128;

    for (int it = 0; it < 16; ++it) {
        int idx = tid + it * 256;
        int row = idx >> 5;
        int c4  = (idx & 31) << 2;
        float4 v = make_float4(0.f, 0.f, 0.f, 0.f);
        int grow = node0 + row;
        if (grow < N) v = *(const float4*)(src + (size_t)grow * DIM + c4);
        bf16x4 b;
        b[0] = (__bf16)v.x; b[1] = (__bf16)v.y; b[2] = (__bf16)v.z; b[3] = (__bf16)v.w;
        *(bf16x4*)&sA[row][c4] = b;
    }

    const int wave = tid >> 6, lane = tid & 63;
    const int rbase = wave * 32;
    const int lrow = lane & 15;
    const int lk   = (lane >> 4) * 8;

    for (int j = 0; j < nj; ++j) {
        __syncthreads();
        const float* Wj = W + (size_t)j * DIM * DIM;
        for (int it = 0; it < 16; ++it) {
            int idx = tid + it * 256;
            int k  = idx >> 5;
            int c4 = (idx & 31) << 2;
            float4 v = *(const float4*)(Wj + k * DIM + c4);
            sB[c4 + 0][k] = (__bf16)v.x;
            sB[c4 + 1][k] = (__bf16)v.y;
            sB[c4 + 2][k] = (__bf16)v.z;
            sB[c4 + 3][k] = (__bf16)v.w;
        }
        __syncthreads();

        f32x4 acc[2][8];
        #pragma unroll
        for (int rt = 0; rt < 2; ++rt)
            #pragma unroll
            for (int ct = 0; ct < 8; ++ct) acc[rt][ct] = (f32x4){0.f, 0.f, 0.f, 0.f};

        #pragma unroll
        for (int ks = 0; ks < 4; ++ks) {
            int k0 = ks * 32 + lk;
            bf16x8 a0 = *(const bf16x8*)&sA[rbase + lrow][k0];
            bf16x8 a1 = *(const bf16x8*)&sA[rbase + 16 + lrow][k0];
            #pragma unroll
            for (int ct = 0; ct < 8; ++ct) {
                bf16x8 b = *(const bf16x8*)&sB[ct * 16 + lrow][k0];
                acc[0][ct] = __builtin_amdgcn_mfma_f32_16x16x32_bf16(a0, b, acc[0][ct], 0, 0, 0);
                acc[1][ct] = __builtin_amdgcn_mfma_f32_16x16x32_bf16(a1, b, acc[1][ct], 0, 0, 0);
            }
        }

        __bf16* dj = dst + (size_t)j * N * DIM;
        #pragma unroll
        for (int rt = 0; rt < 2; ++rt) {
            int row0 = node0 + rbase + rt * 16 + (lane >> 4) * 4;
            #pragma unroll
            for (int r = 0; r < 4; ++r) {
                int row = row0 + r;
                if (row < N) {
                    #pragma unroll
                    for (int ct = 0; ct < 8; ++ct)
                        dj[(size_t)row * DIM + ct * 16 + lrow] = (__bf16)acc[rt][ct][r];
                }
            }
        }
    }
}

// ---------------------------------------------------------------------------
// CSR build: count -> 3-kernel exclusive scan -> fill.
// After fill, offs[n] = END offset of node n (post-increment trick);
// start(n) = (n==0) ? 0 : offs[n-1].
// ---------------------------------------------------------------------------
__global__ __launch_bounds__(256) void csr_count(const int* __restrict__ idx, int stride,
                                                 int* __restrict__ offs, int E)
{
    int e = blockIdx.x * 256 + threadIdx.x;
    if (e >= E) return;
    atomicAdd(&offs[idx[(size_t)e * stride + 1]], 1);
}

#define SCAN_CHUNK 1024  // 256 threads x 4 elems

__global__ __launch_bounds__(256) void scan_s1(int* __restrict__ data,
                                               int* __restrict__ partials, int n)
{
    __shared__ int lds[256];
    const int t = threadIdx.x;
    const int base = blockIdx.x * SCAN_CHUNK + t * 4;
    int v[4];
    #pragma unroll
    for (int i = 0; i < 4; ++i) v[i] = (base + i < n) ? data[base + i] : 0;
    int tsum = v[0] + v[1] + v[2] + v[3];
    lds[t] = tsum; __syncthreads();
    for (int off = 1; off < 256; off <<= 1) {
        int x = (t >= off) ? lds[t - off] : 0;
        __syncthreads();
        lds[t] += x;
        __syncthreads();
    }
    if (t == 255) partials[blockIdx.x] = lds[255];
    int run = lds[t] - tsum;  // exclusive prefix for this thread's first elem
    #pragma unroll
    for (int i = 0; i < 4; ++i) {
        int nv = run; run += v[i];
        if (base + i < n) data[base + i] = nv;
    }
}

__global__ __launch_bounds__(128) void scan_s2(int* __restrict__ partials, int nb)
{
    __shared__ int lds[128];
    const int t = threadIdx.x;
    int v = (t < nb) ? partials[t] : 0;
    lds[t] = v; __syncthreads();
    for (int off = 1; off < 128; off <<= 1) {
        int x = (t >= off) ? lds[t - off] : 0;
        __syncthreads();
        lds[t] += x;
        __syncthreads();
    }
    if (t < nb) partials[t] = lds[t] - v;  // exclusive
}

__global__ __launch_bounds__(256) void scan_s3(int* __restrict__ data,
                                               const int* __restrict__ partials, int n)
{
    const int add = partials[blockIdx.x];
    const int base = blockIdx.x * SCAN_CHUNK + threadIdx.x * 4;
    #pragma unroll
    for (int i = 0; i < 4; ++i)
        if (base + i < n) data[base + i] += add;
}

__global__ __launch_bounds__(256) void csr_fill(const int* __restrict__ idx, int stride,
                                                int* __restrict__ offs,
                                                int* __restrict__ elist, int E)
{
    int e = blockIdx.x * 256 + threadIdx.x;
    if (e >= E) return;
    int i1 = idx[(size_t)e * stride + 1];
    int slot = atomicAdd(&offs[i1], 1);
    elist[slot] = e;
}

__device__ __forceinline__ float silu(float x) { return x / (1.f + __expf(-x)); }

// ---------------------------------------------------------------------------
// Gather-sum per destination node (no atomics). One wave per node, 2 ch/lane.
// agg[n] = sum_e silu(P0[i0]+P1[n]+P2[i2](+P3[i3])+v*wl+b), written as bf16.
// ---------------------------------------------------------------------------
__global__ __launch_bounds__(256) void gather3(const __bf16* __restrict__ P,
                                               const int* __restrict__ idx,
                                               const float* __restrict__ val,
                                               const float* __restrict__ wlast,
                                               const float* __restrict__ bias,
                                               const int* __restrict__ offs,
                                               const int* __restrict__ elist,
                                               __bf16* __restrict__ agg, int N)
{
    int n = blockIdx.x * 4 + (threadIdx.x >> 6);
    if (n >= N) return;
    int lane = threadIdx.x & 63;
    int f = lane * 2;
    const size_t NB = (size_t)N * DIM;
    int start = (n == 0) ? 0 : offs[n - 1];
    int end = offs[n];
    float2 wl = *(const float2*)(wlast + f);
    float2 bb = *(const float2*)(bias + f);
    bf16x2 p1 = *(const bf16x2*)(P + NB + (size_t)n * DIM + f);
    float base0 = (float)p1[0] + bb.x;
    float base1 = (float)p1[1] + bb.y;
    float a0 = 0.f, a1 = 0.f;
    for (int s = start; s < end; ++s) {
        int e = elist[s];
        int i0 = idx[3 * (size_t)e + 0];
        int i2 = idx[3 * (size_t)e + 2];
        float v = val[e];
        bf16x2 p0 = *(const bf16x2*)(P +          (size_t)i0 * DIM + f);
        bf16x2 p2 = *(const bf16x2*)(P + 2 * NB + (size_t)i2 * DIM + f);
        float m0 = (float)p0[0] + (float)p2[0] + v * wl.x + base0;
        float m1 = (float)p0[1] + (float)p2[1] + v * wl.y + base1;
        a0 += silu(m0);
        a1 += silu(m1);
    }
    bf16x2 o; o[0] = (__bf16)a0; o[1] = (__bf16)a1;
    *(bf16x2*)(agg + (size_t)n * DIM + f) = o;
}

__global__ __launch_bounds__(256) void gather4(const __bf16* __restrict__ P,
                                               const int* __restrict__ idx,
                                               const float* __restrict__ val,
                                               const float* __restrict__ wlast,
                                               const float* __restrict__ bias,
                                               const int* __restrict__ offs,
                                               const int* __restrict__ elist,
                                               __bf16* __restrict__ agg, int N)
{
    int n = blockIdx.x * 4 + (threadIdx.x >> 6);
    if (n >= N) return;
    int lane = threadIdx.x & 63;
    int f = lane * 2;
    const size_t NB = (size_t)N * DIM;
    int start = (n == 0) ? 0 : offs[n - 1];
    int end = offs[n];
    float2 wl = *(const float2*)(wlast + f);
    float2 bb = *(const float2*)(bias + f);
    bf16x2 p1 = *(const bf16x2*)(P + NB + (size_t)n * DIM + f);
    float base0 = (float)p1[0] + bb.x;
    float base1 = (float)p1[1] + bb.y;
    float a0 = 0.f, a1 = 0.f;
    for (int s = start; s < end; ++s) {
        int e = elist[s];
        int i0 = idx[4 * (size_t)e + 0];
        int i2 = idx[4 * (size_t)e + 2];
        int i3 = idx[4 * (size_t)e + 3];
        float v = val[e];
        bf16x2 p0 = *(const bf16x2*)(P +          (size_t)i0 * DIM + f);
        bf16x2 p2 = *(const bf16x2*)(P + 2 * NB + (size_t)i2 * DIM + f);
        bf16x2 p3 = *(const bf16x2*)(P + 3 * NB + (size_t)i3 * DIM + f);
        float m0 = (float)p0[0] + (float)p2[0] + (float)p3[0] + v * wl.x + base0;
        float m1 = (float)p0[1] + (float)p2[1] + (float)p3[1] + v * wl.y + base1;
        a0 += silu(m0);
        a1 += silu(m1);
    }
    bf16x2 o; o[0] = (__bf16)a0; o[1] = (__bf16)a1;
    *(bf16x2*)(agg + (size_t)n * DIM + f) = o;
}

// ---------------------------------------------------------------------------
// out[row][col] = resid[row][col] + (bh?bh[col]:0) + (srcf?srcf@W0:0) + srcb@W{0|1}
// nsrc==2: stage srcf (f32) with W[0] then srcb (bf16) with W[1].
// nsrc==1: stage srcb (bf16) with W[0] only. resid may equal out.
// ---------------------------------------------------------------------------
__global__ __launch_bounds__(256) void update_gemm(const float* __restrict__ srcf,
                                                   const __bf16* __restrict__ srcb,
                                                   const float* __restrict__ Wh,
                                                   const float* __restrict__ bh,
                                                   const float* resid,
                                                   float* out, int nsrc, int N)
{
    __shared__ __bf16 sA[128][LDS_STRIDE];
    __shared__ __bf16 sB[128][LDS_STRIDE];
    const int tid = threadIdx.x;
    const int node0 = blockIdx.x * 128;
    const int wave = tid >> 6, lane = tid & 63;
    const int rbase = wave * 32;
    const int lrow = lane & 15;
    const int lk   = (lane >> 4) * 8;

    f32x4 acc[2][8];
    #pragma unroll
    for (int rt = 0; rt < 2; ++rt)
        #pragma unroll
        for (int ct = 0; ct < 8; ++ct) acc[rt][ct] = (f32x4){0.f, 0.f, 0.f, 0.f};

    for (int s = 0; s < nsrc; ++s) {
        __syncthreads();
        const bool use_f32 = (nsrc == 2 && s == 0);
        if (use_f32) {
            for (int it = 0; it < 16; ++it) {
                int idx = tid + it * 256;
                int row = idx >> 5;
                int c4  = (idx & 31) << 2;
                float4 v = make_float4(0.f, 0.f, 0.f, 0.f);
                int grow = node0 + row;
                if (grow < N) v = *(const float4*)(srcf + (size_t)grow * DIM + c4);
                bf16x4 b;
                b[0] = (__bf16)v.x; b[1] = (__bf16)v.y; b[2] = (__bf16)v.z; b[3] = (__bf16)v.w;
                *(bf16x4*)&sA[row][c4] = b;
            }
        } else {
            for (int it = 0; it < 8; ++it) {
                int idx = tid + it * 256;
                int row = idx >> 4;
                int c8  = (idx & 15) << 3;
                bf16x8 v = {};
                int grow = node0 + row;
                if (grow < N) v = *(const bf16x8*)(srcb + (size_t)grow * DIM + c8);
                *(bf16x8*)&sA[row][c8] = v;
            }
        }
        const float* Ws = Wh + (size_t)s * DIM * DIM;
        for (int it = 0; it < 16; ++it) {
            int idx = tid + it * 256;
            int k  = idx >> 5;
            int c4 = (idx & 31) << 2;
            float4 v = *(const float4*)(Ws + k * DIM + c4);
            sB[c4 + 0][k] = (__bf16)v.x;
            sB[c4 + 1][k] = (__bf16)v.y;
            sB[c4 + 2][k] = (__bf16)v.z;
            sB[c4 + 3][k] = (__bf16)v.w;
        }
        __syncthreads();
        #pragma unroll
        for (int ks = 0; ks < 4; ++ks) {
            int k0 = ks * 32 + lk;
            bf16x8 a0 = *(const bf16x8*)&sA[rbase + lrow][k0];
            bf16x8 a1 = *(const bf16x8*)&sA[rbase + 16 + lrow][k0];
            #pragma unroll
            for (int ct = 0; ct < 8; ++ct) {
                bf16x8 b = *(const bf16x8*)&sB[ct * 16 + lrow][k0];
                acc[0][ct] = __builtin_amdgcn_mfma_f32_16x16x32_bf16(a0, b, acc[0][ct], 0, 0, 0);
                acc[1][ct] = __builtin_amdgcn_mfma_f32_16x16x32_bf16(a1, b, acc[1][ct], 0, 0, 0);
            }
        }
    }

    #pragma unroll
    for (int rt = 0; rt < 2; ++rt) {
        int row0 = node0 + rbase + rt * 16 + (lane >> 4) * 4;
        #pragma unroll
        for (int r = 0; r < 4; ++r) {
            int row = row0 + r;
            if (row < N) {
                #pragma unroll
                for (int ct = 0; ct < 8; ++ct) {
                    int col = ct * 16 + lrow;
                    float base = resid[(size_t)row * DIM + col] + (bh ? bh[col] : 0.f);
                    out[(size_t)row * DIM + col] = base + acc[rt][ct][r];
                }
            }
        }
    }
}

// ---------------------------------------------------------------------------
// ws layout (~130.5 MB):
//   P:        4 * NB bf16  (102.4 MB)
//   agg:      NB bf16      (25.6 MB)
//   offs:     (N+1) int
//   partials: NBLK int
//   elist:    E int        (2 MB)
// ---------------------------------------------------------------------------
static inline size_t align16(size_t x) { return (x + 15) & ~(size_t)15; }

extern "C" void kernel_launch(void* const* d_in, const int* in_sizes, int n_in,
                              void* d_out, int out_size, void* d_ws, size_t ws_size,
                              hipStream_t stream)
{
    const float* h     = (const float*)d_in[0];
    const int*   a_idx = (const int*)d_in[1];
    const float* a_val = (const float*)d_in[2];
    const int*   d_idx = (const int*)d_in[3];
    const float* d_val = (const float*)d_in[4];
    const float* W_a   = (const float*)d_in[5];
    const float* b_a   = (const float*)d_in[6];
    const float* W_d   = (const float*)d_in[7];
    const float* b_d   = (const float*)d_in[8];
    const float* W_h   = (const float*)d_in[9];
    const float* b_h   = (const float*)d_in[10];
    float* out = (float*)d_out;

    const int N  = in_sizes[0] / DIM;   // 100000
    const int EA = in_sizes[2];         // 500000
    const int ED = in_sizes[4];         // 500000
    const int Emax = (EA > ED) ? EA : ED;
    const size_t NB = (size_t)N * DIM;
    const int NBLK = (N + SCAN_CHUNK - 1) / SCAN_CHUNK;  // 98 <= 128

    size_t off = 0;
    __bf16* P   = (__bf16*)((char*)d_ws + off); off = align16(off + 4 * NB * sizeof(__bf16));
    __bf16* agg = (__bf16*)((char*)d_ws + off); off = align16(off + NB * sizeof(__bf16));
    int* offs     = (int*)((char*)d_ws + off);  off = align16(off + (size_t)(N + 1) * sizeof(int));
    int* partials = (int*)((char*)d_ws + off);  off = align16(off + (size_t)NBLK * sizeof(int));
    int* elist    = (int*)((char*)d_ws + off);  off = align16(off + (size_t)Emax * sizeof(int));
    if (ws_size < off) return;  // diagnostic guard: clean absmax failure => ws too small

    const int NT = (N + 127) / 128;
    const int GE_A = (EA + 255) / 256, GE_D = (ED + 255) / 256;
    const int GN = (N + 3) / 4;

    // ---- angle path ----
    pre_gemm<<<NT, 256, 0, stream>>>(h, W_a, P, 3, N);
    hipMemsetAsync(offs, 0, (size_t)(N + 1) * sizeof(int), stream);
    csr_count<<<GE_A, 256, 0, stream>>>(a_idx, 3, offs, EA);
    scan_s1<<<NBLK, 256, 0, stream>>>(offs, partials, N);
    scan_s2<<<1, 128, 0, stream>>>(partials, NBLK);
    scan_s3<<<NBLK, 256, 0, stream>>>(offs, partials, N);
    csr_fill<<<GE_A, 256, 0, stream>>>(a_idx, 3, offs, elist, EA);
    gather3<<<GN, 256, 0, stream>>>(P, a_idx, a_val, W_a + 384 * DIM, b_a, offs, elist, agg, N);
    // out = h + b_h + h@Wh0 + agg_a@Wh1
    update_gemm<<<NT, 256, 0, stream>>>(h, agg, W_h, b_h, h, out, 2, N);

    // ---- dihedral path (reuses P, agg, CSR buffers) ----
    pre_gemm<<<NT, 256, 0, stream>>>(h, W_d, P, 4, N);
    hipMemsetAsync(offs, 0, (size_t)(N + 1) * sizeof(int), stream);
    csr_count<<<GE_D, 256, 0, stream>>>(d_idx, 4, offs, ED);
    scan_s1<<<NBLK, 256, 0, stream>>>(offs, partials, N);
    scan_s2<<<1, 128, 0, stream>>>(partials, NBLK);
    scan_s3<<<NBLK, 256, 0, stream>>>(offs, partials, N);
    csr_fill<<<GE_D, 256, 0, stream>>>(d_idx, 4, offs, elist, ED);
    gather4<<<GN, 256, 0, stream>>>(P, d_idx, d_val, W_d + 512 * DIM, b_d, offs, elist, agg, N);
    // out += agg_d@Wh2
    update_gemm<<<NT, 256, 0, stream>>>(nullptr, agg, W_h + 2 * DIM * DIM, nullptr, out, out, 1, N);
}

// Round 4
// 528.324 us; speedup vs baseline: 2.2174x; 1.1933x over previous
//
#include <hip/hip_runtime.h>
#include <hip/hip_bf16.h>

#define DIM 128
#define LDS_STRIDE 136  // 128 + 8 bf16 pad: 272B row stride, 16B-aligned, 2-way-max bank alias (free)

typedef __attribute__((ext_vector_type(8))) __bf16 bf16x8;
typedef __attribute__((ext_vector_type(4))) __bf16 bf16x4;
typedef __attribute__((ext_vector_type(2))) __bf16 bf16x2;
typedef __attribute__((ext_vector_type(4))) float f32x4;

// ---------------------------------------------------------------------------
// pre_gemm, split-by-j: one block = one (128-node tile, j) pair.
// P[j][n][c] = sum_k src[n][k] * W[j*128+k][c], output bf16.
// Bijective XCD-chunk swizzle (m204) so the nj blocks sharing an h-tile land
// on the same XCD -> h tile read hits L2 after the first j.
// ---------------------------------------------------------------------------
__global__ __launch_bounds__(256) void pre_gemm(const float* __restrict__ src,
                                                const float* __restrict__ W,
                                                __bf16* __restrict__ dst,
                                                int nj, int N, int nwg)
{
    __shared__ __bf16 sA[128][LDS_STRIDE];
    __shared__ __bf16 sB[128][LDS_STRIDE];  // transposed: sB[c][k]
    const int tid = threadIdx.x;

    // chunked XCD swizzle: blocks with bid%8==x map to contiguous swz range
    int bid = blockIdx.x;
    int q = nwg >> 3, r = nwg & 7, xcd = bid & 7, pos = bid >> 3;
    int swz = (xcd < r ? xcd * (q + 1) : r * (q + 1) + (xcd - r) * q) + pos;
    const int tile = swz / nj;
    const int j    = swz - tile * nj;
    const int node0 = tile * 128;

    // stage A (h tile, f32 -> bf16)
    for (int it = 0; it < 16; ++it) {
        int idx = tid + it * 256;
        int row = idx >> 5;
        int c4  = (idx & 31) << 2;
        float4 v = make_float4(0.f, 0.f, 0.f, 0.f);
        int grow = node0 + row;
        if (grow < N) v = *(const float4*)(src + (size_t)grow * DIM + c4);
        bf16x4 b;
        b[0] = (__bf16)v.x; b[1] = (__bf16)v.y; b[2] = (__bf16)v.z; b[3] = (__bf16)v.w;
        *(bf16x4*)&sA[row][c4] = b;
    }
    // stage B (W_j transposed)
    const float* Wj = W + (size_t)j * DIM * DIM;
    for (int it = 0; it < 16; ++it) {
        int idx = tid + it * 256;
        int k  = idx >> 5;
        int c4 = (idx & 31) << 2;
        float4 v = *(const float4*)(Wj + k * DIM + c4);
        sB[c4 + 0][k] = (__bf16)v.x;
        sB[c4 + 1][k] = (__bf16)v.y;
        sB[c4 + 2][k] = (__bf16)v.z;
        sB[c4 + 3][k] = (__bf16)v.w;
    }
    __syncthreads();

    const int wave = tid >> 6, lane = tid & 63;
    const int rbase = wave * 32;
    const int lrow = lane & 15;
    const int lk   = (lane >> 4) * 8;

    f32x4 acc[2][8];
    #pragma unroll
    for (int rt = 0; rt < 2; ++rt)
        #pragma unroll
        for (int ct = 0; ct < 8; ++ct) acc[rt][ct] = (f32x4){0.f, 0.f, 0.f, 0.f};

    #pragma unroll
    for (int ks = 0; ks < 4; ++ks) {
        int k0 = ks * 32 + lk;
        bf16x8 a0 = *(const bf16x8*)&sA[rbase + lrow][k0];
        bf16x8 a1 = *(const bf16x8*)&sA[rbase + 16 + lrow][k0];
        #pragma unroll
        for (int ct = 0; ct < 8; ++ct) {
            bf16x8 b = *(const bf16x8*)&sB[ct * 16 + lrow][k0];
            acc[0][ct] = __builtin_amdgcn_mfma_f32_16x16x32_bf16(a0, b, acc[0][ct], 0, 0, 0);
            acc[1][ct] = __builtin_amdgcn_mfma_f32_16x16x32_bf16(a1, b, acc[1][ct], 0, 0, 0);
        }
    }

    __bf16* dj = dst + (size_t)j * N * DIM;
    #pragma unroll
    for (int rt = 0; rt < 2; ++rt) {
        int row0 = node0 + rbase + rt * 16 + (lane >> 4) * 4;
        #pragma unroll
        for (int r = 0; r < 4; ++r) {
            int row = row0 + r;
            if (row < N) {
                #pragma unroll
                for (int ct = 0; ct < 8; ++ct)
                    dj[(size_t)row * DIM + ct * 16 + lrow] = (__bf16)acc[rt][ct][r];
            }
        }
    }
}

// ---------------------------------------------------------------------------
// Joint CSR build for both edge sets: counts in offs[0..N) (angle) and
// offs[N..2N) (dihedral); joint exclusive scan makes dihedral slots start at
// EA automatically. fill packs int4 records with P byte-offsets + val bits.
// After fill, offs[i] = END of segment i (post-increment trick).
// ---------------------------------------------------------------------------
__global__ __launch_bounds__(256) void csr_count_both(const int* __restrict__ a_idx,
                                                      const int* __restrict__ d_idx,
                                                      int* __restrict__ offs,
                                                      int EA, int ED, int N)
{
    int e = blockIdx.x * 256 + threadIdx.x;
    if (e < EA) {
        atomicAdd(&offs[a_idx[3 * (size_t)e + 1]], 1);
    } else if (e < EA + ED) {
        int k = e - EA;
        atomicAdd(&offs[N + d_idx[4 * (size_t)k + 1]], 1);
    }
}

#define SCAN_CHUNK 1024  // 256 threads x 4 elems

__global__ __launch_bounds__(256) void scan_s1(int* __restrict__ data,
                                               int* __restrict__ partials, int n)
{
    __shared__ int lds[256];
    const int t = threadIdx.x;
    const int base = blockIdx.x * SCAN_CHUNK + t * 4;
    int v[4];
    #pragma unroll
    for (int i = 0; i < 4; ++i) v[i] = (base + i < n) ? data[base + i] : 0;
    int tsum = v[0] + v[1] + v[2] + v[3];
    lds[t] = tsum; __syncthreads();
    for (int off = 1; off < 256; off <<= 1) {
        int x = (t >= off) ? lds[t - off] : 0;
        __syncthreads();
        lds[t] += x;
        __syncthreads();
    }
    if (t == 255) partials[blockIdx.x] = lds[255];
    int run = lds[t] - tsum;
    #pragma unroll
    for (int i = 0; i < 4; ++i) {
        int nv = run; run += v[i];
        if (base + i < n) data[base + i] = nv;
    }
}

__global__ __launch_bounds__(256) void scan_s2(int* __restrict__ partials, int nb)
{
    __shared__ int lds[256];
    const int t = threadIdx.x;
    int v = (t < nb) ? partials[t] : 0;
    lds[t] = v; __syncthreads();
    for (int off = 1; off < 256; off <<= 1) {
        int x = (t >= off) ? lds[t - off] : 0;
        __syncthreads();
        lds[t] += x;
        __syncthreads();
    }
    if (t < nb) partials[t] = lds[t] - v;  // exclusive
}

__global__ __launch_bounds__(256) void scan_s3(int* __restrict__ data,
                                               const int* __restrict__ partials, int n)
{
    const int add = partials[blockIdx.x];
    const int base = blockIdx.x * SCAN_CHUNK + threadIdx.x * 4;
    #pragma unroll
    for (int i = 0; i < 4; ++i)
        if (base + i < n) data[base + i] += add;
}

__global__ __launch_bounds__(256) void csr_fill_both(const int* __restrict__ a_idx,
                                                     const float* __restrict__ a_val,
                                                     const int* __restrict__ d_idx,
                                                     const float* __restrict__ d_val,
                                                     int* __restrict__ offs,
                                                     int4* __restrict__ recs,
                                                     int EA, int ED, int N)
{
    int e = blockIdx.x * 256 + threadIdx.x;
    if (e < EA) {
        int i0 = a_idx[3 * (size_t)e + 0];
        int i1 = a_idx[3 * (size_t)e + 1];
        int i2 = a_idx[3 * (size_t)e + 2];
        int slot = atomicAdd(&offs[i1], 1);
        recs[slot] = make_int4(i0 * 256, i2 * 256, __float_as_int(a_val[e]), 0);
    } else if (e < EA + ED) {
        int k = e - EA;
        int i0 = d_idx[4 * (size_t)k + 0];
        int i1 = d_idx[4 * (size_t)k + 1];
        int i2 = d_idx[4 * (size_t)k + 2];
        int i3 = d_idx[4 * (size_t)k + 3];
        int slot = atomicAdd(&offs[N + i1], 1);
        recs[slot] = make_int4(i0 * 256, i2 * 256, i3 * 256, __float_as_int(d_val[k]));
    }
}

__device__ __forceinline__ float silu(float x) { return x / (1.f + __expf(-x)); }

// ---------------------------------------------------------------------------
// Gather-sum per destination node. One wave per node, 2 ch/lane, unroll x2.
// Packed recs: one wave-uniform 16B load per edge; P loads are base+byteoff.
// ---------------------------------------------------------------------------
__global__ __launch_bounds__(256) void gather3(const __bf16* __restrict__ P,
                                               const float* __restrict__ wlast,
                                               const float* __restrict__ bias,
                                               const int* __restrict__ offs,
                                               const int4* __restrict__ recs,
                                               __bf16* __restrict__ agg, int N)
{
    int n = blockIdx.x * 4 + (threadIdx.x >> 6);
    if (n >= N) return;
    int lane = threadIdx.x & 63;
    int f = lane * 2;
    const size_t NBb = (size_t)N * DIM * 2;  // bytes per P buffer
    const char* P0b = (const char*)P;
    const char* P2b = P0b + 2 * NBb;
    int fb = f * 2;  // byte offset of this lane's channel pair
    int start = (n == 0) ? 0 : offs[n - 1];
    int end = offs[n];
    float2 wl = *(const float2*)(wlast + f);
    float2 bb = *(const float2*)(bias + f);
    bf16x2 p1 = *(const bf16x2*)(P0b + NBb + (size_t)n * 256 + fb);
    float base0 = (float)p1[0] + bb.x;
    float base1 = (float)p1[1] + bb.y;
    float a0 = 0.f, a1 = 0.f;
    int s = start;
    for (; s + 1 < end; s += 2) {
        int4 rA = recs[s];
        int4 rB = recs[s + 1];
        bf16x2 A0 = *(const bf16x2*)(P0b + rA.x + fb);
        bf16x2 A2 = *(const bf16x2*)(P2b + rA.y + fb);
        bf16x2 B0 = *(const bf16x2*)(P0b + rB.x + fb);
        bf16x2 B2 = *(const bf16x2*)(P2b + rB.y + fb);
        float vA = __int_as_float(rA.z), vB = __int_as_float(rB.z);
        float mA0 = (float)A0[0] + (float)A2[0] + vA * wl.x + base0;
        float mA1 = (float)A0[1] + (float)A2[1] + vA * wl.y + base1;
        float mB0 = (float)B0[0] + (float)B2[0] + vB * wl.x + base0;
        float mB1 = (float)B0[1] + (float)B2[1] + vB * wl.y + base1;
        a0 += silu(mA0) + silu(mB0);
        a1 += silu(mA1) + silu(mB1);
    }
    if (s < end) {
        int4 rA = recs[s];
        bf16x2 A0 = *(const bf16x2*)(P0b + rA.x + fb);
        bf16x2 A2 = *(const bf16x2*)(P2b + rA.y + fb);
        float vA = __int_as_float(rA.z);
        float mA0 = (float)A0[0] + (float)A2[0] + vA * wl.x + base0;
        float mA1 = (float)A0[1] + (float)A2[1] + vA * wl.y + base1;
        a0 += silu(mA0);
        a1 += silu(mA1);
    }
    bf16x2 o; o[0] = (__bf16)a0; o[1] = (__bf16)a1;
    *(bf16x2*)(agg + (size_t)n * DIM + f) = o;
}

__global__ __launch_bounds__(256) void gather4(const __bf16* __restrict__ P,
                                               const float* __restrict__ wlast,
                                               const float* __restrict__ bias,
                                               const int* __restrict__ offs_d,  // = offs + N
                                               const int4* __restrict__ recs,
                                               __bf16* __restrict__ agg, int N)
{
    int n = blockIdx.x * 4 + (threadIdx.x >> 6);
    if (n >= N) return;
    int lane = threadIdx.x & 63;
    int f = lane * 2;
    const size_t NBb = (size_t)N * DIM * 2;
    const char* P0b = (const char*)P;
    const char* P2b = P0b + 2 * NBb;
    const char* P3b = P0b + 3 * NBb;
    int fb = f * 2;
    int start = offs_d[n - 1];  // n==0 -> offs[N-1] == EA == dihedral base: valid
    int end = offs_d[n];
    float2 wl = *(const float2*)(wlast + f);
    float2 bb = *(const float2*)(bias + f);
    bf16x2 p1 = *(const bf16x2*)(P0b + NBb + (size_t)n * 256 + fb);
    float base0 = (float)p1[0] + bb.x;
    float base1 = (float)p1[1] + bb.y;
    float a0 = 0.f, a1 = 0.f;
    int s = start;
    for (; s + 1 < end; s += 2) {
        int4 rA = recs[s];
        int4 rB = recs[s + 1];
        bf16x2 A0 = *(const bf16x2*)(P0b + rA.x + fb);
        bf16x2 A2 = *(const bf16x2*)(P2b + rA.y + fb);
        bf16x2 A3 = *(const bf16x2*)(P3b + rA.z + fb);
        bf16x2 B0 = *(const bf16x2*)(P0b + rB.x + fb);
        bf16x2 B2 = *(const bf16x2*)(P2b + rB.y + fb);
        bf16x2 B3 = *(const bf16x2*)(P3b + rB.z + fb);
        float vA = __int_as_float(rA.w), vB = __int_as_float(rB.w);
        float mA0 = (float)A0[0] + (float)A2[0] + (float)A3[0] + vA * wl.x + base0;
        float mA1 = (float)A0[1] + (float)A2[1] + (float)A3[1] + vA * wl.y + base1;
        float mB0 = (float)B0[0] + (float)B2[0] + (float)B3[0] + vB * wl.x + base0;
        float mB1 = (float)B0[1] + (float)B2[1] + (float)B3[1] + vB * wl.y + base1;
        a0 += silu(mA0) + silu(mB0);
        a1 += silu(mA1) + silu(mB1);
    }
    if (s < end) {
        int4 rA = recs[s];
        bf16x2 A0 = *(const bf16x2*)(P0b + rA.x + fb);
        bf16x2 A2 = *(const bf16x2*)(P2b + rA.y + fb);
        bf16x2 A3 = *(const bf16x2*)(P3b + rA.z + fb);
        float vA = __int_as_float(rA.w);
        float mA0 = (float)A0[0] + (float)A2[0] + (float)A3[0] + vA * wl.x + base0;
        float mA1 = (float)A0[1] + (float)A2[1] + (float)A3[1] + vA * wl.y + base1;
        a0 += silu(mA0);
        a1 += silu(mA1);
    }
    bf16x2 o; o[0] = (__bf16)a0; o[1] = (__bf16)a1;
    *(bf16x2*)(agg + (size_t)n * DIM + f) = o;
}

// ---------------------------------------------------------------------------
// out = resid + (bh?bh:0) + (srcf?srcf@W0:0) + srcb@W{0|1}.  resid may == out.
// ---------------------------------------------------------------------------
__global__ __launch_bounds__(256) void update_gemm(const float* __restrict__ srcf,
                                                   const __bf16* __restrict__ srcb,
                                                   const float* __restrict__ Wh,
                                                   const float* __restrict__ bh,
                                                   const float* resid,
                                                   float* out, int nsrc, int N)
{
    __shared__ __bf16 sA[128][LDS_STRIDE];
    __shared__ __bf16 sB[128][LDS_STRIDE];
    const int tid = threadIdx.x;
    const int node0 = blockIdx.x * 128;
    const int wave = tid >> 6, lane = tid & 63;
    const int rbase = wave * 32;
    const int lrow = lane & 15;
    const int lk   = (lane >> 4) * 8;

    f32x4 acc[2][8];
    #pragma unroll
    for (int rt = 0; rt < 2; ++rt)
        #pragma unroll
        for (int ct = 0; ct < 8; ++ct) acc[rt][ct] = (f32x4){0.f, 0.f, 0.f, 0.f};

    for (int s = 0; s < nsrc; ++s) {
        __syncthreads();
        const bool use_f32 = (nsrc == 2 && s == 0);
        if (use_f32) {
            for (int it = 0; it < 16; ++it) {
                int idx = tid + it * 256;
                int row = idx >> 5;
                int c4  = (idx & 31) << 2;
                float4 v = make_float4(0.f, 0.f, 0.f, 0.f);
                int grow = node0 + row;
                if (grow < N) v = *(const float4*)(srcf + (size_t)grow * DIM + c4);
                bf16x4 b;
                b[0] = (__bf16)v.x; b[1] = (__bf16)v.y; b[2] = (__bf16)v.z; b[3] = (__bf16)v.w;
                *(bf16x4*)&sA[row][c4] = b;
            }
        } else {
            for (int it = 0; it < 8; ++it) {
                int idx = tid + it * 256;
                int row = idx >> 4;
                int c8  = (idx & 15) << 3;
                bf16x8 v = {};
                int grow = node0 + row;
                if (grow < N) v = *(const bf16x8*)(srcb + (size_t)grow * DIM + c8);
                *(bf16x8*)&sA[row][c8] = v;
            }
        }
        const float* Ws = Wh + (size_t)s * DIM * DIM;
        for (int it = 0; it < 16; ++it) {
            int idx = tid + it * 256;
            int k  = idx >> 5;
            int c4 = (idx & 31) << 2;
            float4 v = *(const float4*)(Ws + k * DIM + c4);
            sB[c4 + 0][k] = (__bf16)v.x;
            sB[c4 + 1][k] = (__bf16)v.y;
            sB[c4 + 2][k] = (__bf16)v.z;
            sB[c4 + 3][k] = (__bf16)v.w;
        }
        __syncthreads();
        #pragma unroll
        for (int ks = 0; ks < 4; ++ks) {
            int k0 = ks * 32 + lk;
            bf16x8 a0 = *(const bf16x8*)&sA[rbase + lrow][k0];
            bf16x8 a1 = *(const bf16x8*)&sA[rbase + 16 + lrow][k0];
            #pragma unroll
            for (int ct = 0; ct < 8; ++ct) {
                bf16x8 b = *(const bf16x8*)&sB[ct * 16 + lrow][k0];
                acc[0][ct] = __builtin_amdgcn_mfma_f32_16x16x32_bf16(a0, b, acc[0][ct], 0, 0, 0);
                acc[1][ct] = __builtin_amdgcn_mfma_f32_16x16x32_bf16(a1, b, acc[1][ct], 0, 0, 0);
            }
        }
    }

    #pragma unroll
    for (int rt = 0; rt < 2; ++rt) {
        int row0 = node0 + rbase + rt * 16 + (lane >> 4) * 4;
        #pragma unroll
        for (int r = 0; r < 4; ++r) {
            int row = row0 + r;
            if (row < N) {
                #pragma unroll
                for (int ct = 0; ct < 8; ++ct) {
                    int col = ct * 16 + lrow;
                    float base = resid[(size_t)row * DIM + col] + (bh ? bh[col] : 0.f);
                    out[(size_t)row * DIM + col] = base + acc[rt][ct][r];
                }
            }
        }
    }
}

// ---------------------------------------------------------------------------
// ws layout (~145 MB; 153.6 MB proven available in R2):
//   P:        4 * NB bf16  (102.4 MB)
//   agg:      NB bf16      (25.6 MB)
//   offs:     2N int       (joint angle+dihedral)
//   partials: 256 int
//   recs:     (EA+ED) int4 (16 MB)
// ---------------------------------------------------------------------------
static inline size_t align16(size_t x) { return (x + 15) & ~(size_t)15; }

extern "C" void kernel_launch(void* const* d_in, const int* in_sizes, int n_in,
                              void* d_out, int out_size, void* d_ws, size_t ws_size,
                              hipStream_t stream)
{
    const float* h     = (const float*)d_in[0];
    const int*   a_idx = (const int*)d_in[1];
    const float* a_val = (const float*)d_in[2];
    const int*   d_idx = (const int*)d_in[3];
    const float* d_val = (const float*)d_in[4];
    const float* W_a   = (const float*)d_in[5];
    const float* b_a   = (const float*)d_in[6];
    const float* W_d   = (const float*)d_in[7];
    const float* b_d   = (const float*)d_in[8];
    const float* W_h   = (const float*)d_in[9];
    const float* b_h   = (const float*)d_in[10];
    float* out = (float*)d_out;

    const int N  = in_sizes[0] / DIM;   // 100000
    const int EA = in_sizes[2];         // 500000
    const int ED = in_sizes[4];         // 500000
    const size_t NB = (size_t)N * DIM;
    const int twoN = 2 * N;
    const int NBLK = (twoN + SCAN_CHUNK - 1) / SCAN_CHUNK;  // 196 <= 256

    size_t off = 0;
    __bf16* P   = (__bf16*)((char*)d_ws + off); off = align16(off + 4 * NB * sizeof(__bf16));
    __bf16* agg = (__bf16*)((char*)d_ws + off); off = align16(off + NB * sizeof(__bf16));
    int* offs     = (int*)((char*)d_ws + off);  off = align16(off + (size_t)twoN * sizeof(int));
    int* partials = (int*)((char*)d_ws + off);  off = align16(off + 256 * sizeof(int));
    int4* recs    = (int4*)((char*)d_ws + off); off = align16(off + (size_t)(EA + ED) * sizeof(int4));
    if (ws_size < off) return;  // diagnostic guard

    const int NT = (N + 127) / 128;        // 782
    const int GE = (EA + ED + 255) / 256;  // both edge sets
    const int GN = (N + 3) / 4;

    // ---- joint CSR build (both paths) ----
    hipMemsetAsync(offs, 0, (size_t)twoN * sizeof(int), stream);
    csr_count_both<<<GE, 256, 0, stream>>>(a_idx, d_idx, offs, EA, ED, N);
    scan_s1<<<NBLK, 256, 0, stream>>>(offs, partials, twoN);
    scan_s2<<<1, 256, 0, stream>>>(partials, NBLK);
    scan_s3<<<NBLK, 256, 0, stream>>>(offs, partials, twoN);
    csr_fill_both<<<GE, 256, 0, stream>>>(a_idx, a_val, d_idx, d_val, offs, recs, EA, ED, N);

    // ---- angle path ----
    {
        int nwg = NT * 3;
        pre_gemm<<<nwg, 256, 0, stream>>>(h, W_a, P, 3, N, nwg);
    }
    gather3<<<GN, 256, 0, stream>>>(P, W_a + 384 * DIM, b_a, offs, recs, agg, N);
    // out = h + b_h + h@Wh0 + agg_a@Wh1
    update_gemm<<<NT, 256, 0, stream>>>(h, agg, W_h, b_h, h, out, 2, N);

    // ---- dihedral path (reuses P, agg) ----
    {
        int nwg = NT * 4;
        pre_gemm<<<nwg, 256, 0, stream>>>(h, W_d, P, 4, N, nwg);
    }
    gather4<<<GN, 256, 0, stream>>>(P, W_d + 512 * DIM, b_d, offs + N, recs, agg, N);
    // out += agg_d@Wh2
    update_gemm<<<NT, 256, 0, stream>>>(nullptr, agg, W_h + 2 * DIM * DIM, nullptr, out, out, 1, N);
}

// Round 5
// 515.517 us; speedup vs baseline: 2.2725x; 1.0248x over previous
//
#include <hip/hip_runtime.h>
#include <hip/hip_bf16.h>

#define DIM 128
#define LDS_STRIDE 136  // 128 + 8 bf16 pad -> 272B row stride; b128 reads 2-way max (free)

typedef __attribute__((ext_vector_type(8))) __bf16 bf16x8;
typedef __attribute__((ext_vector_type(4))) __bf16 bf16x4;
typedef __attribute__((ext_vector_type(2))) __bf16 bf16x2;
typedef __attribute__((ext_vector_type(4))) float f32x4;

// ---------------------------------------------------------------------------
// prep_w: transpose 10 128x128 W blocks (3 W_a, 4 W_d, 3 W_h) into
// Wt[t][c][k] bf16. Writes coalesced (k contiguous); reads stride-512B but
// the whole source is 0.66 MB -> cache-resident. ~163K elements total.
// ---------------------------------------------------------------------------
__global__ __launch_bounds__(256) void prep_w(const float* __restrict__ W_a,
                                              const float* __restrict__ W_d,
                                              const float* __restrict__ W_h,
                                              __bf16* __restrict__ Wt)
{
    int idx = blockIdx.x * 256 + threadIdx.x;   // 10*16384 total
    if (idx >= 10 * 16384) return;
    int t   = idx >> 14;
    int rem = idx & 16383;
    int c   = rem >> 7;
    int k   = rem & 127;
    const float* src;
    if (t < 3)      src = W_a + (size_t)t * 16384;
    else if (t < 7) src = W_d + (size_t)(t - 3) * 16384;
    else            src = W_h + (size_t)(t - 7) * 16384;
    Wt[(size_t)t * 16384 + c * 128 + k] = (__bf16)src[k * 128 + c];
}

// ---------------------------------------------------------------------------
// proj: P[j][n][c] = sum_k h[n][k] * W[jbase+j][k][c], j = 0..nj-1.
// One block = 128-node tile. Only sA in LDS (34 KB -> 4 blocks/CU).
// B-fragments read directly from global Wt (L2-resident, conflict-free).
// A frag: row=lane&15, k=(lane>>4)*8+i ; B frag: col=lane&15, same k
// D frag: col=lane&15, row=(lane>>4)*4+r   (m89-verified)
// ---------------------------------------------------------------------------
__global__ __launch_bounds__(256) void proj(const float* __restrict__ src,
                                            const __bf16* __restrict__ Wt,  // at jbase
                                            __bf16* __restrict__ dst,
                                            int nj, int N)
{
    __shared__ __bf16 sA[128][LDS_STRIDE];
    const int tid = threadIdx.x;
    const int node0 = blockIdx.x * 128;

    // stage h tile (f32 -> bf16), conflict-free writes
    for (int it = 0; it < 16; ++it) {
        int idx = tid + it * 256;
        int row = idx >> 5;
        int c4  = (idx & 31) << 2;
        float4 v = make_float4(0.f, 0.f, 0.f, 0.f);
        int grow = node0 + row;
        if (grow < N) v = *(const float4*)(src + (size_t)grow * DIM + c4);
        bf16x4 b;
        b[0] = (__bf16)v.x; b[1] = (__bf16)v.y; b[2] = (__bf16)v.z; b[3] = (__bf16)v.w;
        *(bf16x4*)&sA[row][c4] = b;
    }
    __syncthreads();

    const int wave = tid >> 6, lane = tid & 63;
    const int rbase = wave * 32;
    const int lrow = lane & 15;
    const int lk   = (lane >> 4) * 8;

    for (int j = 0; j < nj; ++j) {
        const __bf16* Wtj = Wt + (size_t)j * 16384;

        f32x4 acc[2][8];
        #pragma unroll
        for (int rt = 0; rt < 2; ++rt)
            #pragma unroll
            for (int ct = 0; ct < 8; ++ct) acc[rt][ct] = (f32x4){0.f, 0.f, 0.f, 0.f};

        #pragma unroll
        for (int ks = 0; ks < 4; ++ks) {
            int k0 = ks * 32 + lk;
            bf16x8 a0 = *(const bf16x8*)&sA[rbase + lrow][k0];
            bf16x8 a1 = *(const bf16x8*)&sA[rbase + 16 + lrow][k0];
            #pragma unroll
            for (int ct = 0; ct < 8; ++ct) {
                bf16x8 b = *(const bf16x8*)(Wtj + (ct * 16 + lrow) * 128 + k0);
                acc[0][ct] = __builtin_amdgcn_mfma_f32_16x16x32_bf16(a0, b, acc[0][ct], 0, 0, 0);
                acc[1][ct] = __builtin_amdgcn_mfma_f32_16x16x32_bf16(a1, b, acc[1][ct], 0, 0, 0);
            }
        }

        __bf16* dj = dst + (size_t)j * N * DIM;
        #pragma unroll
        for (int rt = 0; rt < 2; ++rt) {
            int row0 = node0 + rbase + rt * 16 + (lane >> 4) * 4;
            #pragma unroll
            for (int r = 0; r < 4; ++r) {
                int row = row0 + r;
                if (row < N) {
                    #pragma unroll
                    for (int ct = 0; ct < 8; ++ct)
                        dj[(size_t)row * DIM + ct * 16 + lrow] = (__bf16)acc[rt][ct][r];
                }
            }
        }
    }
}

// ---------------------------------------------------------------------------
// Joint CSR build (angle offsets in offs[0..N), dihedral in offs[N..2N);
// joint scan puts dihedral slot base at EA automatically).
// ---------------------------------------------------------------------------
__global__ __launch_bounds__(256) void csr_count_both(const int* __restrict__ a_idx,
                                                      const int* __restrict__ d_idx,
                                                      int* __restrict__ offs,
                                                      int EA, int ED, int N)
{
    int e = blockIdx.x * 256 + threadIdx.x;
    if (e < EA) {
        atomicAdd(&offs[a_idx[3 * (size_t)e + 1]], 1);
    } else if (e < EA + ED) {
        int k = e - EA;
        atomicAdd(&offs[N + d_idx[4 * (size_t)k + 1]], 1);
    }
}

#define SCAN_CHUNK 1024

__global__ __launch_bounds__(256) void scan_s1(int* __restrict__ data,
                                               int* __restrict__ partials, int n)
{
    __shared__ int lds[256];
    const int t = threadIdx.x;
    const int base = blockIdx.x * SCAN_CHUNK + t * 4;
    int v[4];
    #pragma unroll
    for (int i = 0; i < 4; ++i) v[i] = (base + i < n) ? data[base + i] : 0;
    int tsum = v[0] + v[1] + v[2] + v[3];
    lds[t] = tsum; __syncthreads();
    for (int off = 1; off < 256; off <<= 1) {
        int x = (t >= off) ? lds[t - off] : 0;
        __syncthreads();
        lds[t] += x;
        __syncthreads();
    }
    if (t == 255) partials[blockIdx.x] = lds[255];
    int run = lds[t] - tsum;
    #pragma unroll
    for (int i = 0; i < 4; ++i) {
        int nv = run; run += v[i];
        if (base + i < n) data[base + i] = nv;
    }
}

__global__ __launch_bounds__(256) void scan_s2(int* __restrict__ partials, int nb)
{
    __shared__ int lds[256];
    const int t = threadIdx.x;
    int v = (t < nb) ? partials[t] : 0;
    lds[t] = v; __syncthreads();
    for (int off = 1; off < 256; off <<= 1) {
        int x = (t >= off) ? lds[t - off] : 0;
        __syncthreads();
        lds[t] += x;
        __syncthreads();
    }
    if (t < nb) partials[t] = lds[t] - v;
}

__global__ __launch_bounds__(256) void scan_s3(int* __restrict__ data,
                                               const int* __restrict__ partials, int n)
{
    const int add = partials[blockIdx.x];
    const int base = blockIdx.x * SCAN_CHUNK + threadIdx.x * 4;
    #pragma unroll
    for (int i = 0; i < 4; ++i)
        if (base + i < n) data[base + i] += add;
}

__global__ __launch_bounds__(256) void csr_fill_both(const int* __restrict__ a_idx,
                                                     const float* __restrict__ a_val,
                                                     const int* __restrict__ d_idx,
                                                     const float* __restrict__ d_val,
                                                     int* __restrict__ offs,
                                                     int4* __restrict__ recs,
                                                     int EA, int ED, int N)
{
    int e = blockIdx.x * 256 + threadIdx.x;
    if (e < EA) {
        int i0 = a_idx[3 * (size_t)e + 0];
        int i1 = a_idx[3 * (size_t)e + 1];
        int i2 = a_idx[3 * (size_t)e + 2];
        int slot = atomicAdd(&offs[i1], 1);
        recs[slot] = make_int4(i0 * 256, i2 * 256, __float_as_int(a_val[e]), 0);
    } else if (e < EA + ED) {
        int k = e - EA;
        int i0 = d_idx[4 * (size_t)k + 0];
        int i1 = d_idx[4 * (size_t)k + 1];
        int i2 = d_idx[4 * (size_t)k + 2];
        int i3 = d_idx[4 * (size_t)k + 3];
        int slot = atomicAdd(&offs[N + i1], 1);
        recs[slot] = make_int4(i0 * 256, i2 * 256, i3 * 256, __float_as_int(d_val[k]));
    }
}

__device__ __forceinline__ float silu(float x) { return x / (1.f + __expf(-x)); }

// ---------------------------------------------------------------------------
// Gather-sum per destination node; one wave/node, 2 ch/lane, unroll x2.
// ---------------------------------------------------------------------------
__global__ __launch_bounds__(256) void gather3(const __bf16* __restrict__ P,
                                               const float* __restrict__ wlast,
                                               const float* __restrict__ bias,
                                               const int* __restrict__ offs,
                                               const int4* __restrict__ recs,
                                               __bf16* __restrict__ agg, int N)
{
    int n = blockIdx.x * 4 + (threadIdx.x >> 6);
    if (n >= N) return;
    int lane = threadIdx.x & 63;
    int f = lane * 2;
    const size_t NBb = (size_t)N * DIM * 2;
    const char* P0b = (const char*)P;
    const char* P2b = P0b + 2 * NBb;
    int fb = f * 2;
    int start = (n == 0) ? 0 : offs[n - 1];
    int end = offs[n];
    float2 wl = *(const float2*)(wlast + f);
    float2 bb = *(const float2*)(bias + f);
    bf16x2 p1 = *(const bf16x2*)(P0b + NBb + (size_t)n * 256 + fb);
    float base0 = (float)p1[0] + bb.x;
    float base1 = (float)p1[1] + bb.y;
    float a0 = 0.f, a1 = 0.f;
    int s = start;
    for (; s + 1 < end; s += 2) {
        int4 rA = recs[s];
        int4 rB = recs[s + 1];
        bf16x2 A0 = *(const bf16x2*)(P0b + rA.x + fb);
        bf16x2 A2 = *(const bf16x2*)(P2b + rA.y + fb);
        bf16x2 B0 = *(const bf16x2*)(P0b + rB.x + fb);
        bf16x2 B2 = *(const bf16x2*)(P2b + rB.y + fb);
        float vA = __int_as_float(rA.z), vB = __int_as_float(rB.z);
        float mA0 = (float)A0[0] + (float)A2[0] + vA * wl.x + base0;
        float mA1 = (float)A0[1] + (float)A2[1] + vA * wl.y + base1;
        float mB0 = (float)B0[0] + (float)B2[0] + vB * wl.x + base0;
        float mB1 = (float)B0[1] + (float)B2[1] + vB * wl.y + base1;
        a0 += silu(mA0) + silu(mB0);
        a1 += silu(mA1) + silu(mB1);
    }
    if (s < end) {
        int4 rA = recs[s];
        bf16x2 A0 = *(const bf16x2*)(P0b + rA.x + fb);
        bf16x2 A2 = *(const bf16x2*)(P2b + rA.y + fb);
        float vA = __int_as_float(rA.z);
        float mA0 = (float)A0[0] + (float)A2[0] + vA * wl.x + base0;
        float mA1 = (float)A0[1] + (float)A2[1] + vA * wl.y + base1;
        a0 += silu(mA0);
        a1 += silu(mA1);
    }
    bf16x2 o; o[0] = (__bf16)a0; o[1] = (__bf16)a1;
    *(bf16x2*)(agg + (size_t)n * DIM + f) = o;
}

__global__ __launch_bounds__(256) void gather4(const __bf16* __restrict__ P,
                                               const float* __restrict__ wlast,
                                               const float* __restrict__ bias,
                                               const int* __restrict__ offs_d,  // = offs + N
                                               const int4* __restrict__ recs,
                                               __bf16* __restrict__ agg, int N)
{
    int n = blockIdx.x * 4 + (threadIdx.x >> 6);
    if (n >= N) return;
    int lane = threadIdx.x & 63;
    int f = lane * 2;
    const size_t NBb = (size_t)N * DIM * 2;
    const char* P0b = (const char*)P;
    const char* P2b = P0b + 2 * NBb;
    const char* P3b = P0b + 3 * NBb;
    int fb = f * 2;
    int start = offs_d[n - 1];  // n==0 -> offs[N-1] == EA == dihedral base
    int end = offs_d[n];
    float2 wl = *(const float2*)(wlast + f);
    float2 bb = *(const float2*)(bias + f);
    bf16x2 p1 = *(const bf16x2*)(P0b + NBb + (size_t)n * 256 + fb);
    float base0 = (float)p1[0] + bb.x;
    float base1 = (float)p1[1] + bb.y;
    float a0 = 0.f, a1 = 0.f;
    int s = start;
    for (; s + 1 < end; s += 2) {
        int4 rA = recs[s];
        int4 rB = recs[s + 1];
        bf16x2 A0 = *(const bf16x2*)(P0b + rA.x + fb);
        bf16x2 A2 = *(const bf16x2*)(P2b + rA.y + fb);
        bf16x2 A3 = *(const bf16x2*)(P3b + rA.z + fb);
        bf16x2 B0 = *(const bf16x2*)(P0b + rB.x + fb);
        bf16x2 B2 = *(const bf16x2*)(P2b + rB.y + fb);
        bf16x2 B3 = *(const bf16x2*)(P3b + rB.z + fb);
        float vA = __int_as_float(rA.w), vB = __int_as_float(rB.w);
        float mA0 = (float)A0[0] + (float)A2[0] + (float)A3[0] + vA * wl.x + base0;
        float mA1 = (float)A0[1] + (float)A2[1] + (float)A3[1] + vA * wl.y + base1;
        float mB0 = (float)B0[0] + (float)B2[0] + (float)B3[0] + vB * wl.x + base0;
        float mB1 = (float)B0[1] + (float)B2[1] + (float)B3[1] + vB * wl.y + base1;
        a0 += silu(mA0) + silu(mB0);
        a1 += silu(mA1) + silu(mB1);
    }
    if (s < end) {
        int4 rA = recs[s];
        bf16x2 A0 = *(const bf16x2*)(P0b + rA.x + fb);
        bf16x2 A2 = *(const bf16x2*)(P2b + rA.y + fb);
        bf16x2 A3 = *(const bf16x2*)(P3b + rA.z + fb);
        float vA = __int_as_float(rA.w);
        float mA0 = (float)A0[0] + (float)A2[0] + (float)A3[0] + vA * wl.x + base0;
        float mA1 = (float)A0[1] + (float)A2[1] + (float)A3[1] + vA * wl.y + base1;
        a0 += silu(mA0);
        a1 += silu(mA1);
    }
    bf16x2 o; o[0] = (__bf16)a0; o[1] = (__bf16)a1;
    *(bf16x2*)(agg + (size_t)n * DIM + f) = o;
}

// ---------------------------------------------------------------------------
// update: out = resid + (bh?bh:0) + (srcf?srcf@Wt[0]:0) + srcb@Wt[last]
// Wt points at the first of nsrc pre-transposed 128x128 bf16 blocks.
// Only sA in LDS; B-frags from global Wt. resid may == out (same-thread RMW).
// ---------------------------------------------------------------------------
__global__ __launch_bounds__(256) void update_gemm(const float* __restrict__ srcf,
                                                   const __bf16* __restrict__ srcb,
                                                   const __bf16* __restrict__ Wt,
                                                   const float* __restrict__ bh,
                                                   const float* resid,
                                                   float* out, int nsrc, int N)
{
    __shared__ __bf16 sA[128][LDS_STRIDE];
    const int tid = threadIdx.x;
    const int node0 = blockIdx.x * 128;
    const int wave = tid >> 6, lane = tid & 63;
    const int rbase = wave * 32;
    const int lrow = lane & 15;
    const int lk   = (lane >> 4) * 8;

    f32x4 acc[2][8];
    #pragma unroll
    for (int rt = 0; rt < 2; ++rt)
        #pragma unroll
        for (int ct = 0; ct < 8; ++ct) acc[rt][ct] = (f32x4){0.f, 0.f, 0.f, 0.f};

    for (int s = 0; s < nsrc; ++s) {
        __syncthreads();
        const bool use_f32 = (nsrc == 2 && s == 0);
        if (use_f32) {
            for (int it = 0; it < 16; ++it) {
                int idx = tid + it * 256;
                int row = idx >> 5;
                int c4  = (idx & 31) << 2;
                float4 v = make_float4(0.f, 0.f, 0.f, 0.f);
                int grow = node0 + row;
                if (grow < N) v = *(const float4*)(srcf + (size_t)grow * DIM + c4);
                bf16x4 b;
                b[0] = (__bf16)v.x; b[1] = (__bf16)v.y; b[2] = (__bf16)v.z; b[3] = (__bf16)v.w;
                *(bf16x4*)&sA[row][c4] = b;
            }
        } else {
            for (int it = 0; it < 8; ++it) {
                int idx = tid + it * 256;
                int row = idx >> 4;
                int c8  = (idx & 15) << 3;
                bf16x8 v = {};
                int grow = node0 + row;
                if (grow < N) v = *(const bf16x8*)(srcb + (size_t)grow * DIM + c8);
                *(bf16x8*)&sA[row][c8] = v;
            }
        }
        __syncthreads();
        const __bf16* Wts = Wt + (size_t)s * 16384;
        #pragma unroll
        for (int ks = 0; ks < 4; ++ks) {
            int k0 = ks * 32 + lk;
            bf16x8 a0 = *(const bf16x8*)&sA[rbase + lrow][k0];
            bf16x8 a1 = *(const bf16x8*)&sA[rbase + 16 + lrow][k0];
            #pragma unroll
            for (int ct = 0; ct < 8; ++ct) {
                bf16x8 b = *(const bf16x8*)(Wts + (ct * 16 + lrow) * 128 + k0);
                acc[0][ct] = __builtin_amdgcn_mfma_f32_16x16x32_bf16(a0, b, acc[0][ct], 0, 0, 0);
                acc[1][ct] = __builtin_amdgcn_mfma_f32_16x16x32_bf16(a1, b, acc[1][ct], 0, 0, 0);
            }
        }
    }

    #pragma unroll
    for (int rt = 0; rt < 2; ++rt) {
        int row0 = node0 + rbase + rt * 16 + (lane >> 4) * 4;
        #pragma unroll
        for (int r = 0; r < 4; ++r) {
            int row = row0 + r;
            if (row < N) {
                #pragma unroll
                for (int ct = 0; ct < 8; ++ct) {
                    int col = ct * 16 + lrow;
                    float base = resid[(size_t)row * DIM + col] + (bh ? bh[col] : 0.f);
                    out[(size_t)row * DIM + col] = base + acc[rt][ct][r];
                }
            }
        }
    }
}

// ---------------------------------------------------------------------------
// ws layout (~145.4 MB; 153.6 MB proven in R2):
//   P:    4 * NB bf16 (102.4 MB)     agg: NB bf16 (25.6 MB)
//   offs: 2N int                      partials: 256 int
//   recs: (EA+ED) int4 (16 MB)        Wt: 10*16384 bf16 (0.33 MB)
// ---------------------------------------------------------------------------
static inline size_t align16(size_t x) { return (x + 15) & ~(size_t)15; }

extern "C" void kernel_launch(void* const* d_in, const int* in_sizes, int n_in,
                              void* d_out, int out_size, void* d_ws, size_t ws_size,
                              hipStream_t stream)
{
    const float* h     = (const float*)d_in[0];
    const int*   a_idx = (const int*)d_in[1];
    const float* a_val = (const float*)d_in[2];
    const int*   d_idx = (const int*)d_in[3];
    const float* d_val = (const float*)d_in[4];
    const float* W_a   = (const float*)d_in[5];
    const float* b_a   = (const float*)d_in[6];
    const float* W_d   = (const float*)d_in[7];
    const float* b_d   = (const float*)d_in[8];
    const float* W_h   = (const float*)d_in[9];
    const float* b_h   = (const float*)d_in[10];
    float* out = (float*)d_out;

    const int N  = in_sizes[0] / DIM;   // 100000
    const int EA = in_sizes[2];         // 500000
    const int ED = in_sizes[4];         // 500000
    const size_t NB = (size_t)N * DIM;
    const int twoN = 2 * N;
    const int NBLK = (twoN + SCAN_CHUNK - 1) / SCAN_CHUNK;  // 196 <= 256

    size_t off = 0;
    __bf16* P   = (__bf16*)((char*)d_ws + off); off = align16(off + 4 * NB * sizeof(__bf16));
    __bf16* agg = (__bf16*)((char*)d_ws + off); off = align16(off + NB * sizeof(__bf16));
    int* offs     = (int*)((char*)d_ws + off);  off = align16(off + (size_t)twoN * sizeof(int));
    int* partials = (int*)((char*)d_ws + off);  off = align16(off + 256 * sizeof(int));
    int4* recs    = (int4*)((char*)d_ws + off); off = align16(off + (size_t)(EA + ED) * sizeof(int4));
    __bf16* Wt  = (__bf16*)((char*)d_ws + off); off = align16(off + (size_t)10 * 16384 * sizeof(__bf16));
    if (ws_size < off) return;  // diagnostic guard

    const int NT = (N + 127) / 128;        // 782
    const int GE = (EA + ED + 255) / 256;
    const int GN = (N + 3) / 4;

    // weight transpose (0.33 MB, stays cache-hot)
    prep_w<<<(10 * 16384 + 255) / 256, 256, 0, stream>>>(W_a, W_d, W_h, Wt);

    // joint CSR build
    hipMemsetAsync(offs, 0, (size_t)twoN * sizeof(int), stream);
    csr_count_both<<<GE, 256, 0, stream>>>(a_idx, d_idx, offs, EA, ED, N);
    scan_s1<<<NBLK, 256, 0, stream>>>(offs, partials, twoN);
    scan_s2<<<1, 256, 0, stream>>>(partials, NBLK);
    scan_s3<<<NBLK, 256, 0, stream>>>(offs, partials, twoN);
    csr_fill_both<<<GE, 256, 0, stream>>>(a_idx, a_val, d_idx, d_val, offs, recs, EA, ED, N);

    // ---- angle path: Wt blocks 0..2 ----
    proj<<<NT, 256, 0, stream>>>(h, Wt, P, 3, N);
    gather3<<<GN, 256, 0, stream>>>(P, W_a + 384 * DIM, b_a, offs, recs, agg, N);
    // out = h + b_h + h@Wh0 + agg_a@Wh1   (Wt blocks 7,8)
    update_gemm<<<NT, 256, 0, stream>>>(h, agg, Wt + (size_t)7 * 16384, b_h, h, out, 2, N);

    // ---- dihedral path: Wt blocks 3..6 (reuses P, agg) ----
    proj<<<NT, 256, 0, stream>>>(h, Wt + (size_t)3 * 16384, P, 4, N);
    gather4<<<GN, 256, 0, stream>>>(P, W_d + 512 * DIM, b_d, offs + N, recs, agg, N);
    // out += agg_d@Wh2   (Wt block 9)
    update_gemm<<<NT, 256, 0, stream>>>(nullptr, agg, Wt + (size_t)9 * 16384, nullptr, out, out, 1, N);
}

// Round 6
// 458.046 us; speedup vs baseline: 2.5576x; 1.1255x over previous
//
#include <hip/hip_runtime.h>
#include <hip/hip_bf16.h>

#define DIM 128
#define LDS_STRIDE 136  // 128 + 8 bf16 pad -> 272B row stride; ds_read_b128 conflict-light

typedef __attribute__((ext_vector_type(8))) __bf16 bf16x8;
typedef __attribute__((ext_vector_type(4))) __bf16 bf16x4;
typedef __attribute__((ext_vector_type(2))) __bf16 bf16x2;
typedef __attribute__((ext_vector_type(4))) float f32x4;

// ---------------------------------------------------------------------------
// prep_w: transpose 10 128x128 W blocks (3 W_a, 4 W_d, 3 W_h) into
// Wt[t][c][k] bf16 (0.33 MB total, L2-resident).
// ---------------------------------------------------------------------------
__global__ __launch_bounds__(256) void prep_w(const float* __restrict__ W_a,
                                              const float* __restrict__ W_d,
                                              const float* __restrict__ W_h,
                                              __bf16* __restrict__ Wt)
{
    int idx = blockIdx.x * 256 + threadIdx.x;
    if (idx >= 10 * 16384) return;
    int t   = idx >> 14;
    int rem = idx & 16383;
    int c   = rem >> 7;
    int k   = rem & 127;
    const float* src;
    if (t < 3)      src = W_a + (size_t)t * 16384;
    else if (t < 7) src = W_d + (size_t)(t - 3) * 16384;
    else            src = W_h + (size_t)(t - 7) * 16384;
    Wt[(size_t)t * 16384 + c * 128 + k] = (__bf16)src[k * 128 + c];
}

// stage one pre-transposed 128x128 bf16 W block into sB (straight copy,
// coalesced 16B writes, no transpose -> no bank conflicts)
__device__ __forceinline__ void stage_wt(const __bf16* __restrict__ Wtj,
                                         __bf16 (*sB)[LDS_STRIDE], int tid)
{
    for (int it = 0; it < 8; ++it) {
        int idx = tid + it * 256;       // 2048 chunks of 8 bf16
        int c  = idx >> 4;
        int k8 = (idx & 15) << 3;
        *(bf16x8*)&sB[c][k8] = *(const bf16x8*)(Wtj + c * 128 + k8);
    }
}

// load one A-fragment pair set directly from global (f32 source), in-register
// cvt. afrag[rt][ks] covers rows rbase+rt*16+lrow, k = ks*32+lk .. +8.
__device__ __forceinline__ void load_afrag_f32(const float* __restrict__ src,
                                               int node0, int rbase, int lrow, int lk,
                                               int N, bf16x8 afrag[2][4])
{
    #pragma unroll
    for (int rt = 0; rt < 2; ++rt) {
        int row = node0 + rbase + rt * 16 + lrow;
        const float* rp = src + (size_t)row * DIM;
        #pragma unroll
        for (int ks = 0; ks < 4; ++ks) {
            float4 v0 = make_float4(0.f, 0.f, 0.f, 0.f), v1 = v0;
            if (row < N) {
                v0 = *(const float4*)(rp + ks * 32 + lk);
                v1 = *(const float4*)(rp + ks * 32 + lk + 4);
            }
            bf16x8 a;
            a[0] = (__bf16)v0.x; a[1] = (__bf16)v0.y; a[2] = (__bf16)v0.z; a[3] = (__bf16)v0.w;
            a[4] = (__bf16)v1.x; a[5] = (__bf16)v1.y; a[6] = (__bf16)v1.z; a[7] = (__bf16)v1.w;
            afrag[rt][ks] = a;
        }
    }
}

__device__ __forceinline__ void load_afrag_bf16(const __bf16* __restrict__ src,
                                                int node0, int rbase, int lrow, int lk,
                                                int N, bf16x8 afrag[2][4])
{
    #pragma unroll
    for (int rt = 0; rt < 2; ++rt) {
        int row = node0 + rbase + rt * 16 + lrow;
        const __bf16* rp = src + (size_t)row * DIM;
        #pragma unroll
        for (int ks = 0; ks < 4; ++ks) {
            bf16x8 a = {};
            if (row < N) a = *(const bf16x8*)(rp + ks * 32 + lk);
            afrag[rt][ks] = a;
        }
    }
}

// ---------------------------------------------------------------------------
// proj: P[j][n][c] = sum_k h[n][k]*W[j][k][c].  A in registers (global->cvt),
// B staged in single 34KB LDS buffer per j.  4 blocks/CU.
// A frag: row=lane&15, k=(lane>>4)*8+i ; D frag: col=lane&15, row=(lane>>4)*4+r
// ---------------------------------------------------------------------------
__global__ __launch_bounds__(256, 4) void proj(const float* __restrict__ src,
                                               const __bf16* __restrict__ Wt,
                                               __bf16* __restrict__ dst,
                                               int nj, int N)
{
    __shared__ __bf16 sB[128][LDS_STRIDE];
    const int tid = threadIdx.x;
    const int node0 = blockIdx.x * 128;
    const int wave = tid >> 6, lane = tid & 63;
    const int rbase = wave * 32;
    const int lrow = lane & 15;
    const int lk   = (lane >> 4) * 8;

    bf16x8 afrag[2][4];
    load_afrag_f32(src, node0, rbase, lrow, lk, N, afrag);

    for (int j = 0; j < nj; ++j) {
        __syncthreads();  // previous j's MFMA done reading sB
        stage_wt(Wt + (size_t)j * 16384, sB, tid);
        __syncthreads();

        f32x4 acc[2][8];
        #pragma unroll
        for (int rt = 0; rt < 2; ++rt)
            #pragma unroll
            for (int ct = 0; ct < 8; ++ct) acc[rt][ct] = (f32x4){0.f, 0.f, 0.f, 0.f};

        #pragma unroll
        for (int ks = 0; ks < 4; ++ks) {
            int k0 = ks * 32 + lk;
            #pragma unroll
            for (int ct = 0; ct < 8; ++ct) {
                bf16x8 b = *(const bf16x8*)&sB[ct * 16 + lrow][k0];
                acc[0][ct] = __builtin_amdgcn_mfma_f32_16x16x32_bf16(afrag[0][ks], b, acc[0][ct], 0, 0, 0);
                acc[1][ct] = __builtin_amdgcn_mfma_f32_16x16x32_bf16(afrag[1][ks], b, acc[1][ct], 0, 0, 0);
            }
        }

        __bf16* dj = dst + (size_t)j * N * DIM;
        #pragma unroll
        for (int rt = 0; rt < 2; ++rt) {
            int row0 = node0 + rbase + rt * 16 + (lane >> 4) * 4;
            #pragma unroll
            for (int r = 0; r < 4; ++r) {
                int row = row0 + r;
                if (row < N) {
                    #pragma unroll
                    for (int ct = 0; ct < 8; ++ct)
                        dj[(size_t)row * DIM + ct * 16 + lrow] = (__bf16)acc[rt][ct][r];
                }
            }
        }
    }
}

// ---------------------------------------------------------------------------
// Joint CSR build (angle offsets in offs[0..N), dihedral in offs[N..2N)).
// ---------------------------------------------------------------------------
__global__ __launch_bounds__(256) void csr_count_both(const int* __restrict__ a_idx,
                                                      const int* __restrict__ d_idx,
                                                      int* __restrict__ offs,
                                                      int EA, int ED, int N)
{
    int e = blockIdx.x * 256 + threadIdx.x;
    if (e < EA) {
        atomicAdd(&offs[a_idx[3 * (size_t)e + 1]], 1);
    } else if (e < EA + ED) {
        int k = e - EA;
        atomicAdd(&offs[N + d_idx[4 * (size_t)k + 1]], 1);
    }
}

#define SCAN_CHUNK 1024

__global__ __launch_bounds__(256) void scan_s1(int* __restrict__ data,
                                               int* __restrict__ partials, int n)
{
    __shared__ int lds[256];
    const int t = threadIdx.x;
    const int base = blockIdx.x * SCAN_CHUNK + t * 4;
    int v[4];
    #pragma unroll
    for (int i = 0; i < 4; ++i) v[i] = (base + i < n) ? data[base + i] : 0;
    int tsum = v[0] + v[1] + v[2] + v[3];
    lds[t] = tsum; __syncthreads();
    for (int off = 1; off < 256; off <<= 1) {
        int x = (t >= off) ? lds[t - off] : 0;
        __syncthreads();
        lds[t] += x;
        __syncthreads();
    }
    if (t == 255) partials[blockIdx.x] = lds[255];
    int run = lds[t] - tsum;
    #pragma unroll
    for (int i = 0; i < 4; ++i) {
        int nv = run; run += v[i];
        if (base + i < n) data[base + i] = nv;
    }
}

__global__ __launch_bounds__(256) void scan_s2(int* __restrict__ partials, int nb)
{
    __shared__ int lds[256];
    const int t = threadIdx.x;
    int v = (t < nb) ? partials[t] : 0;
    lds[t] = v; __syncthreads();
    for (int off = 1; off < 256; off <<= 1) {
        int x = (t >= off) ? lds[t - off] : 0;
        __syncthreads();
        lds[t] += x;
        __syncthreads();
    }
    if (t < nb) partials[t] = lds[t] - v;
}

__global__ __launch_bounds__(256) void scan_s3(int* __restrict__ data,
                                               const int* __restrict__ partials, int n)
{
    const int add = partials[blockIdx.x];
    const int base = blockIdx.x * SCAN_CHUNK + threadIdx.x * 4;
    #pragma unroll
    for (int i = 0; i < 4; ++i)
        if (base + i < n) data[base + i] += add;
}

__global__ __launch_bounds__(256) void csr_fill_both(const int* __restrict__ a_idx,
                                                     const float* __restrict__ a_val,
                                                     const int* __restrict__ d_idx,
                                                     const float* __restrict__ d_val,
                                                     int* __restrict__ offs,
                                                     int4* __restrict__ recs,
                                                     int EA, int ED, int N)
{
    int e = blockIdx.x * 256 + threadIdx.x;
    if (e < EA) {
        int i0 = a_idx[3 * (size_t)e + 0];
        int i1 = a_idx[3 * (size_t)e + 1];
        int i2 = a_idx[3 * (size_t)e + 2];
        int slot = atomicAdd(&offs[i1], 1);
        recs[slot] = make_int4(i0 * 256, i2 * 256, __float_as_int(a_val[e]), 0);
    } else if (e < EA + ED) {
        int k = e - EA;
        int i0 = d_idx[4 * (size_t)k + 0];
        int i1 = d_idx[4 * (size_t)k + 1];
        int i2 = d_idx[4 * (size_t)k + 2];
        int i3 = d_idx[4 * (size_t)k + 3];
        int slot = atomicAdd(&offs[N + i1], 1);
        recs[slot] = make_int4(i0 * 256, i2 * 256, i3 * 256, __float_as_int(d_val[k]));
    }
}

__device__ __forceinline__ float silu(float x) { return x / (1.f + __expf(-x)); }

// ---------------------------------------------------------------------------
// Gather-sum per destination node; one wave/node, 2 ch/lane, unroll x2.
// ---------------------------------------------------------------------------
__global__ __launch_bounds__(256) void gather3(const __bf16* __restrict__ P,
                                               const float* __restrict__ wlast,
                                               const float* __restrict__ bias,
                                               const int* __restrict__ offs,
                                               const int4* __restrict__ recs,
                                               __bf16* __restrict__ agg, int N)
{
    int n = blockIdx.x * 4 + (threadIdx.x >> 6);
    if (n >= N) return;
    int lane = threadIdx.x & 63;
    int f = lane * 2;
    const size_t NBb = (size_t)N * DIM * 2;
    const char* P0b = (const char*)P;
    const char* P2b = P0b + 2 * NBb;
    int fb = f * 2;
    int start = (n == 0) ? 0 : offs[n - 1];
    int end = offs[n];
    float2 wl = *(const float2*)(wlast + f);
    float2 bb = *(const float2*)(bias + f);
    bf16x2 p1 = *(const bf16x2*)(P0b + NBb + (size_t)n * 256 + fb);
    float base0 = (float)p1[0] + bb.x;
    float base1 = (float)p1[1] + bb.y;
    float a0 = 0.f, a1 = 0.f;
    int s = start;
    for (; s + 1 < end; s += 2) {
        int4 rA = recs[s];
        int4 rB = recs[s + 1];
        bf16x2 A0 = *(const bf16x2*)(P0b + rA.x + fb);
        bf16x2 A2 = *(const bf16x2*)(P2b + rA.y + fb);
        bf16x2 B0 = *(const bf16x2*)(P0b + rB.x + fb);
        bf16x2 B2 = *(const bf16x2*)(P2b + rB.y + fb);
        float vA = __int_as_float(rA.z), vB = __int_as_float(rB.z);
        float mA0 = (float)A0[0] + (float)A2[0] + vA * wl.x + base0;
        float mA1 = (float)A0[1] + (float)A2[1] + vA * wl.y + base1;
        float mB0 = (float)B0[0] + (float)B2[0] + vB * wl.x + base0;
        float mB1 = (float)B0[1] + (float)B2[1] + vB * wl.y + base1;
        a0 += silu(mA0) + silu(mB0);
        a1 += silu(mA1) + silu(mB1);
    }
    if (s < end) {
        int4 rA = recs[s];
        bf16x2 A0 = *(const bf16x2*)(P0b + rA.x + fb);
        bf16x2 A2 = *(const bf16x2*)(P2b + rA.y + fb);
        float vA = __int_as_float(rA.z);
        float mA0 = (float)A0[0] + (float)A2[0] + vA * wl.x + base0;
        float mA1 = (float)A0[1] + (float)A2[1] + vA * wl.y + base1;
        a0 += silu(mA0);
        a1 += silu(mA1);
    }
    bf16x2 o; o[0] = (__bf16)a0; o[1] = (__bf16)a1;
    *(bf16x2*)(agg + (size_t)n * DIM + f) = o;
}

__global__ __launch_bounds__(256) void gather4(const __bf16* __restrict__ P,
                                               const float* __restrict__ wlast,
                                               const float* __restrict__ bias,
                                               const int* __restrict__ offs_d,
                                               const int4* __restrict__ recs,
                                               __bf16* __restrict__ agg, int N)
{
    int n = blockIdx.x * 4 + (threadIdx.x >> 6);
    if (n >= N) return;
    int lane = threadIdx.x & 63;
    int f = lane * 2;
    const size_t NBb = (size_t)N * DIM * 2;
    const char* P0b = (const char*)P;
    const char* P2b = P0b + 2 * NBb;
    const char* P3b = P0b + 3 * NBb;
    int fb = f * 2;
    int start = offs_d[n - 1];  // n==0 -> offs[N-1] == EA == dihedral base
    int end = offs_d[n];
    float2 wl = *(const float2*)(wlast + f);
    float2 bb = *(const float2*)(bias + f);
    bf16x2 p1 = *(const bf16x2*)(P0b + NBb + (size_t)n * 256 + fb);
    float base0 = (float)p1[0] + bb.x;
    float base1 = (float)p1[1] + bb.y;
    float a0 = 0.f, a1 = 0.f;
    int s = start;
    for (; s + 1 < end; s += 2) {
        int4 rA = recs[s];
        int4 rB = recs[s + 1];
        bf16x2 A0 = *(const bf16x2*)(P0b + rA.x + fb);
        bf16x2 A2 = *(const bf16x2*)(P2b + rA.y + fb);
        bf16x2 A3 = *(const bf16x2*)(P3b + rA.z + fb);
        bf16x2 B0 = *(const bf16x2*)(P0b + rB.x + fb);
        bf16x2 B2 = *(const bf16x2*)(P2b + rB.y + fb);
        bf16x2 B3 = *(const bf16x2*)(P3b + rB.z + fb);
        float vA = __int_as_float(rA.w), vB = __int_as_float(rB.w);
        float mA0 = (float)A0[0] + (float)A2[0] + (float)A3[0] + vA * wl.x + base0;
        float mA1 = (float)A0[1] + (float)A2[1] + (float)A3[1] + vA * wl.y + base1;
        float mB0 = (float)B0[0] + (float)B2[0] + (float)B3[0] + vB * wl.x + base0;
        float mB1 = (float)B0[1] + (float)B2[1] + (float)B3[1] + vB * wl.y + base1;
        a0 += silu(mA0) + silu(mB0);
        a1 += silu(mA1) + silu(mB1);
    }
    if (s < end) {
        int4 rA = recs[s];
        bf16x2 A0 = *(const bf16x2*)(P0b + rA.x + fb);
        bf16x2 A2 = *(const bf16x2*)(P2b + rA.y + fb);
        bf16x2 A3 = *(const bf16x2*)(P3b + rA.z + fb);
        float vA = __int_as_float(rA.w);
        float mA0 = (float)A0[0] + (float)A2[0] + (float)A3[0] + vA * wl.x + base0;
        float mA1 = (float)A0[1] + (float)A2[1] + (float)A3[1] + vA * wl.y + base1;
        a0 += silu(mA0);
        a1 += silu(mA1);
    }
    bf16x2 o; o[0] = (__bf16)a0; o[1] = (__bf16)a1;
    *(bf16x2*)(agg + (size_t)n * DIM + f) = o;
}

// ---------------------------------------------------------------------------
// update: out = resid + (bh?bh:0) + (srcf?srcf@Wt[0]:0) + srcb@Wt[last]
// A in registers (global->cvt), B in single LDS buffer. resid may == out.
// ---------------------------------------------------------------------------
__global__ __launch_bounds__(256, 4) void update_gemm(const float* __restrict__ srcf,
                                                      const __bf16* __restrict__ srcb,
                                                      const __bf16* __restrict__ Wt,
                                                      const float* __restrict__ bh,
                                                      const float* resid,
                                                      float* out, int nsrc, int N)
{
    __shared__ __bf16 sB[128][LDS_STRIDE];
    const int tid = threadIdx.x;
    const int node0 = blockIdx.x * 128;
    const int wave = tid >> 6, lane = tid & 63;
    const int rbase = wave * 32;
    const int lrow = lane & 15;
    const int lk   = (lane >> 4) * 8;

    f32x4 acc[2][8];
    #pragma unroll
    for (int rt = 0; rt < 2; ++rt)
        #pragma unroll
        for (int ct = 0; ct < 8; ++ct) acc[rt][ct] = (f32x4){0.f, 0.f, 0.f, 0.f};

    for (int s = 0; s < nsrc; ++s) {
        __syncthreads();
        stage_wt(Wt + (size_t)s * 16384, sB, tid);

        bf16x8 afrag[2][4];
        if (nsrc == 2 && s == 0) load_afrag_f32(srcf, node0, rbase, lrow, lk, N, afrag);
        else                     load_afrag_bf16(srcb, node0, rbase, lrow, lk, N, afrag);
        __syncthreads();

        #pragma unroll
        for (int ks = 0; ks < 4; ++ks) {
            int k0 = ks * 32 + lk;
            #pragma unroll
            for (int ct = 0; ct < 8; ++ct) {
                bf16x8 b = *(const bf16x8*)&sB[ct * 16 + lrow][k0];
                acc[0][ct] = __builtin_amdgcn_mfma_f32_16x16x32_bf16(afrag[0][ks], b, acc[0][ct], 0, 0, 0);
                acc[1][ct] = __builtin_amdgcn_mfma_f32_16x16x32_bf16(afrag[1][ks], b, acc[1][ct], 0, 0, 0);
            }
        }
    }

    #pragma unroll
    for (int rt = 0; rt < 2; ++rt) {
        int row0 = node0 + rbase + rt * 16 + (lane >> 4) * 4;
        #pragma unroll
        for (int r = 0; r < 4; ++r) {
            int row = row0 + r;
            if (row < N) {
                #pragma unroll
                for (int ct = 0; ct < 8; ++ct) {
                    int col = ct * 16 + lrow;
                    float base = resid[(size_t)row * DIM + col] + (bh ? bh[col] : 0.f);
                    out[(size_t)row * DIM + col] = base + acc[rt][ct][r];
                }
            }
        }
    }
}

// ---------------------------------------------------------------------------
// ws layout (~145.4 MB; 153.6 MB proven in R2):
//   P: 4*NB bf16 (102.4 MB)  agg: NB bf16 (25.6 MB)
//   offs: 2N int   partials: 256 int   recs: (EA+ED) int4 (16 MB)   Wt: 0.33 MB
// ---------------------------------------------------------------------------
static inline size_t align16(size_t x) { return (x + 15) & ~(size_t)15; }

extern "C" void kernel_launch(void* const* d_in, const int* in_sizes, int n_in,
                              void* d_out, int out_size, void* d_ws, size_t ws_size,
                              hipStream_t stream)
{
    const float* h     = (const float*)d_in[0];
    const int*   a_idx = (const int*)d_in[1];
    const float* a_val = (const float*)d_in[2];
    const int*   d_idx = (const int*)d_in[3];
    const float* d_val = (const float*)d_in[4];
    const float* W_a   = (const float*)d_in[5];
    const float* b_a   = (const float*)d_in[6];
    const float* W_d   = (const float*)d_in[7];
    const float* b_d   = (const float*)d_in[8];
    const float* W_h   = (const float*)d_in[9];
    const float* b_h   = (const float*)d_in[10];
    float* out = (float*)d_out;

    const int N  = in_sizes[0] / DIM;   // 100000
    const int EA = in_sizes[2];         // 500000
    const int ED = in_sizes[4];         // 500000
    const size_t NB = (size_t)N * DIM;
    const int twoN = 2 * N;
    const int NBLK = (twoN + SCAN_CHUNK - 1) / SCAN_CHUNK;  // 196 <= 256

    size_t off = 0;
    __bf16* P   = (__bf16*)((char*)d_ws + off); off = align16(off + 4 * NB * sizeof(__bf16));
    __bf16* agg = (__bf16*)((char*)d_ws + off); off = align16(off + NB * sizeof(__bf16));
    int* offs     = (int*)((char*)d_ws + off);  off = align16(off + (size_t)twoN * sizeof(int));
    int* partials = (int*)((char*)d_ws + off);  off = align16(off + 256 * sizeof(int));
    int4* recs    = (int4*)((char*)d_ws + off); off = align16(off + (size_t)(EA + ED) * sizeof(int4));
    __bf16* Wt  = (__bf16*)((char*)d_ws + off); off = align16(off + (size_t)10 * 16384 * sizeof(__bf16));
    if (ws_size < off) return;  // diagnostic guard

    const int NT = (N + 127) / 128;        // 782
    const int GE = (EA + ED + 255) / 256;
    const int GN = (N + 3) / 4;

    prep_w<<<(10 * 16384 + 255) / 256, 256, 0, stream>>>(W_a, W_d, W_h, Wt);

    hipMemsetAsync(offs, 0, (size_t)twoN * sizeof(int), stream);
    csr_count_both<<<GE, 256, 0, stream>>>(a_idx, d_idx, offs, EA, ED, N);
    scan_s1<<<NBLK, 256, 0, stream>>>(offs, partials, twoN);
    scan_s2<<<1, 256, 0, stream>>>(partials, NBLK);
    scan_s3<<<NBLK, 256, 0, stream>>>(offs, partials, twoN);
    csr_fill_both<<<GE, 256, 0, stream>>>(a_idx, a_val, d_idx, d_val, offs, recs, EA, ED, N);

    // ---- angle path: Wt blocks 0..2 ----
    proj<<<NT, 256, 0, stream>>>(h, Wt, P, 3, N);
    gather3<<<GN, 256, 0, stream>>>(P, W_a + 384 * DIM, b_a, offs, recs, agg, N);
    update_gemm<<<NT, 256, 0, stream>>>(h, agg, Wt + (size_t)7 * 16384, b_h, h, out, 2, N);

    // ---- dihedral path: Wt blocks 3..6 ----
    proj<<<NT, 256, 0, stream>>>(h, Wt + (size_t)3 * 16384, P, 4, N);
    gather4<<<GN, 256, 0, stream>>>(P, W_d + 512 * DIM, b_d, offs + N, recs, agg, N);
    update_gemm<<<NT, 256, 0, stream>>>(nullptr, agg, Wt + (size_t)9 * 16384, nullptr, out, out, 1, N);
}

// Round 7
// 439.089 us; speedup vs baseline: 2.6680x; 1.0432x over previous
//
#include <hip/hip_runtime.h>
#include <hip/hip_bf16.h>

#define DIM 128
#define LDS_STRIDE 136  // 128 + 8 bf16 pad -> 272B row stride; ds_read_b128 conflict-light

typedef __attribute__((ext_vector_type(8))) __bf16 bf16x8;
typedef __attribute__((ext_vector_type(4))) __bf16 bf16x4;
typedef __attribute__((ext_vector_type(2))) __bf16 bf16x2;
typedef __attribute__((ext_vector_type(4))) float f32x4;

// ---------------------------------------------------------------------------
// prep_w: transpose 10 128x128 W blocks into Wt[t][c][k] bf16 (0.33 MB).
// ---------------------------------------------------------------------------
__global__ __launch_bounds__(256) void prep_w(const float* __restrict__ W_a,
                                              const float* __restrict__ W_d,
                                              const float* __restrict__ W_h,
                                              __bf16* __restrict__ Wt)
{
    int idx = blockIdx.x * 256 + threadIdx.x;
    if (idx >= 10 * 16384) return;
    int t   = idx >> 14;
    int rem = idx & 16383;
    int c   = rem >> 7;
    int k   = rem & 127;
    const float* src;
    if (t < 3)      src = W_a + (size_t)t * 16384;
    else if (t < 7) src = W_d + (size_t)(t - 3) * 16384;
    else            src = W_h + (size_t)(t - 7) * 16384;
    Wt[(size_t)t * 16384 + c * 128 + k] = (__bf16)src[k * 128 + c];
}

// stage one pre-transposed 128x128 bf16 W block into sB (straight copy)
__device__ __forceinline__ void stage_wt(const __bf16* __restrict__ Wtj,
                                         __bf16 (*sB)[LDS_STRIDE], int tid)
{
    for (int it = 0; it < 8; ++it) {
        int idx = tid + it * 256;
        int c  = idx >> 4;
        int k8 = (idx & 15) << 3;
        *(bf16x8*)&sB[c][k8] = *(const bf16x8*)(Wtj + c * 128 + k8);
    }
}

// A-fragments for a 64-row tile: wave handles 16 rows (rbase = wave*16).
__device__ __forceinline__ void load_afrag_f32(const float* __restrict__ src,
                                               int row, int lk, int N, bf16x8 afrag[4])
{
    const float* rp = src + (size_t)row * DIM;
    #pragma unroll
    for (int ks = 0; ks < 4; ++ks) {
        float4 v0 = make_float4(0.f, 0.f, 0.f, 0.f), v1 = v0;
        if (row < N) {
            v0 = *(const float4*)(rp + ks * 32 + lk);
            v1 = *(const float4*)(rp + ks * 32 + lk + 4);
        }
        bf16x8 a;
        a[0] = (__bf16)v0.x; a[1] = (__bf16)v0.y; a[2] = (__bf16)v0.z; a[3] = (__bf16)v0.w;
        a[4] = (__bf16)v1.x; a[5] = (__bf16)v1.y; a[6] = (__bf16)v1.z; a[7] = (__bf16)v1.w;
        afrag[ks] = a;
    }
}

__device__ __forceinline__ void load_afrag_bf16(const __bf16* __restrict__ src,
                                                int row, int lk, int N, bf16x8 afrag[4])
{
    const __bf16* rp = src + (size_t)row * DIM;
    #pragma unroll
    for (int ks = 0; ks < 4; ++ks) {
        bf16x8 a = {};
        if (row < N) a = *(const bf16x8*)(rp + ks * 32 + lk);
        afrag[ks] = a;
    }
}

// ---------------------------------------------------------------------------
// proj: P[j][n][c] = sum_k h[n][k]*W[j][k][c].  64-row tiles (grid 1563),
// A in registers, B in one 34KB LDS buffer. 4 blocks/CU.
// ---------------------------------------------------------------------------
__global__ __launch_bounds__(256, 4) void proj(const float* __restrict__ src,
                                               const __bf16* __restrict__ Wt,
                                               __bf16* __restrict__ dst,
                                               int nj, int N)
{
    __shared__ __bf16 sB[128][LDS_STRIDE];
    const int tid = threadIdx.x;
    const int node0 = blockIdx.x * 64;
    const int wave = tid >> 6, lane = tid & 63;
    const int lrow = lane & 15;
    const int lk   = (lane >> 4) * 8;
    const int arow = node0 + wave * 16 + lrow;

    bf16x8 afrag[4];
    load_afrag_f32(src, arow, lk, N, afrag);

    for (int j = 0; j < nj; ++j) {
        __syncthreads();
        stage_wt(Wt + (size_t)j * 16384, sB, tid);
        __syncthreads();

        f32x4 acc[8];
        #pragma unroll
        for (int ct = 0; ct < 8; ++ct) acc[ct] = (f32x4){0.f, 0.f, 0.f, 0.f};

        #pragma unroll
        for (int ks = 0; ks < 4; ++ks) {
            int k0 = ks * 32 + lk;
            #pragma unroll
            for (int ct = 0; ct < 8; ++ct) {
                bf16x8 b = *(const bf16x8*)&sB[ct * 16 + lrow][k0];
                acc[ct] = __builtin_amdgcn_mfma_f32_16x16x32_bf16(afrag[ks], b, acc[ct], 0, 0, 0);
            }
        }

        __bf16* dj = dst + (size_t)j * N * DIM;
        int row0 = node0 + wave * 16 + (lane >> 4) * 4;
        #pragma unroll
        for (int r = 0; r < 4; ++r) {
            int row = row0 + r;
            if (row < N) {
                #pragma unroll
                for (int ct = 0; ct < 8; ++ct)
                    dj[(size_t)row * DIM + ct * 16 + lrow] = (__bf16)acc[ct][r];
            }
        }
    }
}

// ---------------------------------------------------------------------------
// Joint CSR build.
// ---------------------------------------------------------------------------
__global__ __launch_bounds__(256) void csr_count_both(const int* __restrict__ a_idx,
                                                      const int* __restrict__ d_idx,
                                                      int* __restrict__ offs,
                                                      int EA, int ED, int N)
{
    int e = blockIdx.x * 256 + threadIdx.x;
    if (e < EA) {
        atomicAdd(&offs[a_idx[3 * (size_t)e + 1]], 1);
    } else if (e < EA + ED) {
        int k = e - EA;
        atomicAdd(&offs[N + d_idx[4 * (size_t)k + 1]], 1);
    }
}

#define SCAN_CHUNK 1024

__global__ __launch_bounds__(256) void scan_s1(int* __restrict__ data,
                                               int* __restrict__ partials, int n)
{
    __shared__ int lds[256];
    const int t = threadIdx.x;
    const int base = blockIdx.x * SCAN_CHUNK + t * 4;
    int v[4];
    #pragma unroll
    for (int i = 0; i < 4; ++i) v[i] = (base + i < n) ? data[base + i] : 0;
    int tsum = v[0] + v[1] + v[2] + v[3];
    lds[t] = tsum; __syncthreads();
    for (int off = 1; off < 256; off <<= 1) {
        int x = (t >= off) ? lds[t - off] : 0;
        __syncthreads();
        lds[t] += x;
        __syncthreads();
    }
    if (t == 255) partials[blockIdx.x] = lds[255];
    int run = lds[t] - tsum;
    #pragma unroll
    for (int i = 0; i < 4; ++i) {
        int nv = run; run += v[i];
        if (base + i < n) data[base + i] = nv;
    }
}

__global__ __launch_bounds__(256) void scan_s2(int* __restrict__ partials, int nb)
{
    __shared__ int lds[256];
    const int t = threadIdx.x;
    int v = (t < nb) ? partials[t] : 0;
    lds[t] = v; __syncthreads();
    for (int off = 1; off < 256; off <<= 1) {
        int x = (t >= off) ? lds[t - off] : 0;
        __syncthreads();
        lds[t] += x;
        __syncthreads();
    }
    if (t < nb) partials[t] = lds[t] - v;
}

__global__ __launch_bounds__(256) void scan_s3(int* __restrict__ data,
                                               const int* __restrict__ partials, int n)
{
    const int add = partials[blockIdx.x];
    const int base = blockIdx.x * SCAN_CHUNK + threadIdx.x * 4;
    #pragma unroll
    for (int i = 0; i < 4; ++i)
        if (base + i < n) data[base + i] += add;
}

__global__ __launch_bounds__(256) void csr_fill_both(const int* __restrict__ a_idx,
                                                     const float* __restrict__ a_val,
                                                     const int* __restrict__ d_idx,
                                                     const float* __restrict__ d_val,
                                                     int* __restrict__ offs,
                                                     int4* __restrict__ recs,
                                                     int EA, int ED, int N)
{
    int e = blockIdx.x * 256 + threadIdx.x;
    if (e < EA) {
        int i0 = a_idx[3 * (size_t)e + 0];
        int i1 = a_idx[3 * (size_t)e + 1];
        int i2 = a_idx[3 * (size_t)e + 2];
        int slot = atomicAdd(&offs[i1], 1);
        recs[slot] = make_int4(i0 * 256, i2 * 256, __float_as_int(a_val[e]), 0);
    } else if (e < EA + ED) {
        int k = e - EA;
        int i0 = d_idx[4 * (size_t)k + 0];
        int i1 = d_idx[4 * (size_t)k + 1];
        int i2 = d_idx[4 * (size_t)k + 2];
        int i3 = d_idx[4 * (size_t)k + 3];
        int slot = atomicAdd(&offs[N + i1], 1);
        recs[slot] = make_int4(i0 * 256, i2 * 256, i3 * 256, __float_as_int(d_val[k]));
    }
}

__device__ __forceinline__ float silu(float x) { return x / (1.f + __expf(-x)); }

#define GB 8  // gather batch: all rec loads, then all P loads, then compute

// ---------------------------------------------------------------------------
// Batched gather3: one wave/node, 2 ch/lane. Two-phase MLP batching:
// <=8 independent rec loads, then <=16 independent P loads, then compute.
// ---------------------------------------------------------------------------
__global__ __launch_bounds__(256) void gather3(const __bf16* __restrict__ P,
                                               const float* __restrict__ wlast,
                                               const float* __restrict__ bias,
                                               const int* __restrict__ offs,
                                               const int4* __restrict__ recs,
                                               __bf16* __restrict__ agg, int N)
{
    int n = blockIdx.x * 4 + (threadIdx.x >> 6);
    if (n >= N) return;
    int lane = threadIdx.x & 63;
    int f = lane * 2;
    const size_t NBb = (size_t)N * DIM * 2;
    const char* P0b = (const char*)P;
    const char* P2b = P0b + 2 * NBb;
    int fb = f * 2;
    int start = (n == 0) ? 0 : offs[n - 1];
    int end = offs[n];
    float2 wl = *(const float2*)(wlast + f);
    float2 bb = *(const float2*)(bias + f);
    bf16x2 p1 = *(const bf16x2*)(P0b + NBb + (size_t)n * 256 + fb);
    float base0 = (float)p1[0] + bb.x;
    float base1 = (float)p1[1] + bb.y;
    float a0 = 0.f, a1 = 0.f;

    for (int s = start; s < end; s += GB) {
        const int m = end - s;  // wave-uniform
        int4 r[GB];
        #pragma unroll
        for (int b = 0; b < GB; ++b) if (b < m) r[b] = recs[s + b];
        bf16x2 q0[GB], q2[GB];
        #pragma unroll
        for (int b = 0; b < GB; ++b) if (b < m) {
            q0[b] = *(const bf16x2*)(P0b + r[b].x + fb);
            q2[b] = *(const bf16x2*)(P2b + r[b].y + fb);
        }
        #pragma unroll
        for (int b = 0; b < GB; ++b) if (b < m) {
            float v = __int_as_float(r[b].z);
            float m0 = (float)q0[b][0] + (float)q2[b][0] + v * wl.x + base0;
            float m1 = (float)q0[b][1] + (float)q2[b][1] + v * wl.y + base1;
            a0 += silu(m0);
            a1 += silu(m1);
        }
    }
    bf16x2 o; o[0] = (__bf16)a0; o[1] = (__bf16)a1;
    *(bf16x2*)(agg + (size_t)n * DIM + f) = o;
}

__global__ __launch_bounds__(256) void gather4(const __bf16* __restrict__ P,
                                               const float* __restrict__ wlast,
                                               const float* __restrict__ bias,
                                               const int* __restrict__ offs_d,
                                               const int4* __restrict__ recs,
                                               __bf16* __restrict__ agg, int N)
{
    int n = blockIdx.x * 4 + (threadIdx.x >> 6);
    if (n >= N) return;
    int lane = threadIdx.x & 63;
    int f = lane * 2;
    const size_t NBb = (size_t)N * DIM * 2;
    const char* P0b = (const char*)P;
    const char* P2b = P0b + 2 * NBb;
    const char* P3b = P0b + 3 * NBb;
    int fb = f * 2;
    int start = offs_d[n - 1];  // n==0 -> offs[N-1] == EA == dihedral base
    int end = offs_d[n];
    float2 wl = *(const float2*)(wlast + f);
    float2 bb = *(const float2*)(bias + f);
    bf16x2 p1 = *(const bf16x2*)(P0b + NBb + (size_t)n * 256 + fb);
    float base0 = (float)p1[0] + bb.x;
    float base1 = (float)p1[1] + bb.y;
    float a0 = 0.f, a1 = 0.f;

    for (int s = start; s < end; s += GB) {
        const int m = end - s;
        int4 r[GB];
        #pragma unroll
        for (int b = 0; b < GB; ++b) if (b < m) r[b] = recs[s + b];
        bf16x2 q0[GB], q2[GB], q3[GB];
        #pragma unroll
        for (int b = 0; b < GB; ++b) if (b < m) {
            q0[b] = *(const bf16x2*)(P0b + r[b].x + fb);
            q2[b] = *(const bf16x2*)(P2b + r[b].y + fb);
            q3[b] = *(const bf16x2*)(P3b + r[b].z + fb);
        }
        #pragma unroll
        for (int b = 0; b < GB; ++b) if (b < m) {
            float v = __int_as_float(r[b].w);
            float m0 = (float)q0[b][0] + (float)q2[b][0] + (float)q3[b][0] + v * wl.x + base0;
            float m1 = (float)q0[b][1] + (float)q2[b][1] + (float)q3[b][1] + v * wl.y + base1;
            a0 += silu(m0);
            a1 += silu(m1);
        }
    }
    bf16x2 o; o[0] = (__bf16)a0; o[1] = (__bf16)a1;
    *(bf16x2*)(agg + (size_t)n * DIM + f) = o;
}

// ---------------------------------------------------------------------------
// update: out = resid + (bh?bh:0) + (srcf?srcf@Wt[0]:0) + srcb@Wt[last]
// 64-row tiles. A in registers, B in one LDS buffer. resid may == out.
// ---------------------------------------------------------------------------
__global__ __launch_bounds__(256, 4) void update_gemm(const float* __restrict__ srcf,
                                                      const __bf16* __restrict__ srcb,
                                                      const __bf16* __restrict__ Wt,
                                                      const float* __restrict__ bh,
                                                      const float* resid,
                                                      float* out, int nsrc, int N)
{
    __shared__ __bf16 sB[128][LDS_STRIDE];
    const int tid = threadIdx.x;
    const int node0 = blockIdx.x * 64;
    const int wave = tid >> 6, lane = tid & 63;
    const int lrow = lane & 15;
    const int lk   = (lane >> 4) * 8;
    const int arow = node0 + wave * 16 + lrow;

    f32x4 acc[8];
    #pragma unroll
    for (int ct = 0; ct < 8; ++ct) acc[ct] = (f32x4){0.f, 0.f, 0.f, 0.f};

    for (int s = 0; s < nsrc; ++s) {
        __syncthreads();
        stage_wt(Wt + (size_t)s * 16384, sB, tid);

        bf16x8 afrag[4];
        if (nsrc == 2 && s == 0) load_afrag_f32(srcf, arow, lk, N, afrag);
        else                     load_afrag_bf16(srcb, arow, lk, N, afrag);
        __syncthreads();

        #pragma unroll
        for (int ks = 0; ks < 4; ++ks) {
            int k0 = ks * 32 + lk;
            #pragma unroll
            for (int ct = 0; ct < 8; ++ct) {
                bf16x8 b = *(const bf16x8*)&sB[ct * 16 + lrow][k0];
                acc[ct] = __builtin_amdgcn_mfma_f32_16x16x32_bf16(afrag[ks], b, acc[ct], 0, 0, 0);
            }
        }
    }

    int row0 = node0 + wave * 16 + (lane >> 4) * 4;
    #pragma unroll
    for (int r = 0; r < 4; ++r) {
        int row = row0 + r;
        if (row < N) {
            #pragma unroll
            for (int ct = 0; ct < 8; ++ct) {
                int col = ct * 16 + lrow;
                float base = resid[(size_t)row * DIM + col] + (bh ? bh[col] : 0.f);
                out[(size_t)row * DIM + col] = base + acc[ct][r];
            }
        }
    }
}

// ---------------------------------------------------------------------------
// ws layout (~145.4 MB; 153.6 MB proven in R2):
//   P: 4*NB bf16 (102.4 MB)  agg: NB bf16 (25.6 MB)
//   offs: 2N int   partials: 256 int   recs: (EA+ED) int4 (16 MB)   Wt: 0.33 MB
// ---------------------------------------------------------------------------
static inline size_t align16(size_t x) { return (x + 15) & ~(size_t)15; }

extern "C" void kernel_launch(void* const* d_in, const int* in_sizes, int n_in,
                              void* d_out, int out_size, void* d_ws, size_t ws_size,
                              hipStream_t stream)
{
    const float* h     = (const float*)d_in[0];
    const int*   a_idx = (const int*)d_in[1];
    const float* a_val = (const float*)d_in[2];
    const int*   d_idx = (const int*)d_in[3];
    const float* d_val = (const float*)d_in[4];
    const float* W_a   = (const float*)d_in[5];
    const float* b_a   = (const float*)d_in[6];
    const float* W_d   = (const float*)d_in[7];
    const float* b_d   = (const float*)d_in[8];
    const float* W_h   = (const float*)d_in[9];
    const float* b_h   = (const float*)d_in[10];
    float* out = (float*)d_out;

    const int N  = in_sizes[0] / DIM;   // 100000
    const int EA = in_sizes[2];         // 500000
    const int ED = in_sizes[4];         // 500000
    const size_t NB = (size_t)N * DIM;
    const int twoN = 2 * N;
    const int NBLK = (twoN + SCAN_CHUNK - 1) / SCAN_CHUNK;  // 196 <= 256

    size_t off = 0;
    __bf16* P   = (__bf16*)((char*)d_ws + off); off = align16(off + 4 * NB * sizeof(__bf16));
    __bf16* agg = (__bf16*)((char*)d_ws + off); off = align16(off + NB * sizeof(__bf16));
    int* offs     = (int*)((char*)d_ws + off);  off = align16(off + (size_t)twoN * sizeof(int));
    int* partials = (int*)((char*)d_ws + off);  off = align16(off + 256 * sizeof(int));
    int4* recs    = (int4*)((char*)d_ws + off); off = align16(off + (size_t)(EA + ED) * sizeof(int4));
    __bf16* Wt  = (__bf16*)((char*)d_ws + off); off = align16(off + (size_t)10 * 16384 * sizeof(__bf16));
    if (ws_size < off) return;  // diagnostic guard

    const int NT64 = (N + 63) / 64;        // 1563
    const int GE = (EA + ED + 255) / 256;
    const int GN = (N + 3) / 4;

    prep_w<<<(10 * 16384 + 255) / 256, 256, 0, stream>>>(W_a, W_d, W_h, Wt);

    hipMemsetAsync(offs, 0, (size_t)twoN * sizeof(int), stream);
    csr_count_both<<<GE, 256, 0, stream>>>(a_idx, d_idx, offs, EA, ED, N);
    scan_s1<<<NBLK, 256, 0, stream>>>(offs, partials, twoN);
    scan_s2<<<1, 256, 0, stream>>>(partials, NBLK);
    scan_s3<<<NBLK, 256, 0, stream>>>(offs, partials, twoN);
    csr_fill_both<<<GE, 256, 0, stream>>>(a_idx, a_val, d_idx, d_val, offs, recs, EA, ED, N);

    // ---- angle path: Wt blocks 0..2 ----
    proj<<<NT64, 256, 0, stream>>>(h, Wt, P, 3, N);
    gather3<<<GN, 256, 0, stream>>>(P, W_a + 384 * DIM, b_a, offs, recs, agg, N);
    update_gemm<<<NT64, 256, 0, stream>>>(h, agg, Wt + (size_t)7 * 16384, b_h, h, out, 2, N);

    // ---- dihedral path: Wt blocks 3..6 ----
    proj<<<NT64, 256, 0, stream>>>(h, Wt + (size_t)3 * 16384, P, 4, N);
    gather4<<<GN, 256, 0, stream>>>(P, W_d + 512 * DIM, b_d, offs + N, recs, agg, N);
    update_gemm<<<NT64, 256, 0, stream>>>(nullptr, agg, Wt + (size_t)9 * 16384, nullptr, out, out, 1, N);
}

// Round 8
// 385.506 us; speedup vs baseline: 3.0388x; 1.1390x over previous
//
#include <hip/hip_runtime.h>
#include <hip/hip_bf16.h>

#define DIM 128
#define LDS_STRIDE 136  // bf16 stage stride (272B rows)
#define SC_STRIDE 132   // f32 epilogue stride

typedef __attribute__((ext_vector_type(8))) __bf16 bf16x8;
typedef __attribute__((ext_vector_type(4))) __bf16 bf16x4;
typedef __attribute__((ext_vector_type(2))) __bf16 bf16x2;
typedef __attribute__((ext_vector_type(4))) float f32x4;

// ---------------------------------------------------------------------------
// prep_w: transpose 10 128x128 W blocks into Wt[t][c][k] bf16 (0.33 MB).
// ---------------------------------------------------------------------------
__global__ __launch_bounds__(256) void prep_w(const float* __restrict__ W_a,
                                              const float* __restrict__ W_d,
                                              const float* __restrict__ W_h,
                                              __bf16* __restrict__ Wt)
{
    int idx = blockIdx.x * 256 + threadIdx.x;
    if (idx >= 10 * 16384) return;
    int t   = idx >> 14;
    int rem = idx & 16383;
    int c   = rem >> 7;
    int k   = rem & 127;
    const float* src;
    if (t < 3)      src = W_a + (size_t)t * 16384;
    else if (t < 7) src = W_d + (size_t)(t - 3) * 16384;
    else            src = W_h + (size_t)(t - 7) * 16384;
    Wt[(size_t)t * 16384 + c * 128 + k] = (__bf16)src[k * 128 + c];
}

// stage one pre-transposed 128x128 bf16 W block into sB (straight copy)
__device__ __forceinline__ void stage_wt(const __bf16* __restrict__ Wtj,
                                         __bf16 (*sB)[LDS_STRIDE], int tid)
{
    for (int it = 0; it < 8; ++it) {
        int idx = tid + it * 256;
        int c  = idx >> 4;
        int k8 = (idx & 15) << 3;
        *(bf16x8*)&sB[c][k8] = *(const bf16x8*)(Wtj + c * 128 + k8);
    }
}

__device__ __forceinline__ void load_afrag_f32(const float* __restrict__ src,
                                               int row, int lk, int N, bf16x8 afrag[4])
{
    const float* rp = src + (size_t)row * DIM;
    #pragma unroll
    for (int ks = 0; ks < 4; ++ks) {
        float4 v0 = make_float4(0.f, 0.f, 0.f, 0.f), v1 = v0;
        if (row < N) {
            v0 = *(const float4*)(rp + ks * 32 + lk);
            v1 = *(const float4*)(rp + ks * 32 + lk + 4);
        }
        bf16x8 a;
        a[0] = (__bf16)v0.x; a[1] = (__bf16)v0.y; a[2] = (__bf16)v0.z; a[3] = (__bf16)v0.w;
        a[4] = (__bf16)v1.x; a[5] = (__bf16)v1.y; a[6] = (__bf16)v1.z; a[7] = (__bf16)v1.w;
        afrag[ks] = a;
    }
}

__device__ __forceinline__ void load_afrag_bf16(const __bf16* __restrict__ src,
                                                int row, int lk, int N, bf16x8 afrag[4])
{
    const __bf16* rp = src + (size_t)row * DIM;
    #pragma unroll
    for (int ks = 0; ks < 4; ++ks) {
        bf16x8 a = {};
        if (row < N) a = *(const bf16x8*)(rp + ks * 32 + lk);
        afrag[ks] = a;
    }
}

// ---------------------------------------------------------------------------
// proj: P[j][n][c] = sum_k h[n][k]*W[j][k][c]. 64-row tiles, A in registers,
// B in one 34KB LDS buffer. Epilogue repacks acc through LDS -> bf16x4 stores.
// ---------------------------------------------------------------------------
__global__ __launch_bounds__(256, 4) void proj(const float* __restrict__ src,
                                               const __bf16* __restrict__ Wt,
                                               __bf16* __restrict__ dst,
                                               int nj, int N)
{
    __shared__ __bf16 sB[128][LDS_STRIDE];   // also reused as f32 sC[64][SC_STRIDE]
    float* sC = reinterpret_cast<float*>(sB);
    const int tid = threadIdx.x;
    const int node0 = blockIdx.x * 64;
    const int wave = tid >> 6, lane = tid & 63;
    const int lrow = lane & 15;
    const int lk   = (lane >> 4) * 8;
    const int arow = node0 + wave * 16 + lrow;

    bf16x8 afrag[4];
    load_afrag_f32(src, arow, lk, N, afrag);

    for (int j = 0; j < nj; ++j) {
        __syncthreads();  // sC phase / previous j done
        stage_wt(Wt + (size_t)j * 16384, sB, tid);
        __syncthreads();

        f32x4 acc[8];
        #pragma unroll
        for (int ct = 0; ct < 8; ++ct) acc[ct] = (f32x4){0.f, 0.f, 0.f, 0.f};

        #pragma unroll
        for (int ks = 0; ks < 4; ++ks) {
            int k0 = ks * 32 + lk;
            #pragma unroll
            for (int ct = 0; ct < 8; ++ct) {
                bf16x8 b = *(const bf16x8*)&sB[ct * 16 + lrow][k0];
                acc[ct] = __builtin_amdgcn_mfma_f32_16x16x32_bf16(afrag[ks], b, acc[ct], 0, 0, 0);
            }
        }

        __syncthreads();  // all waves done reading sB -> reuse as sC
        {
            int rbase = wave * 16 + (lane >> 4) * 4;
            #pragma unroll
            for (int r = 0; r < 4; ++r)
                #pragma unroll
                for (int ct = 0; ct < 8; ++ct)
                    sC[(rbase + r) * SC_STRIDE + ct * 16 + lrow] = acc[ct][r];
        }
        __syncthreads();

        __bf16* dj = dst + (size_t)j * N * DIM;
        for (int it = 0; it < 8; ++it) {
            int idx = tid + it * 256;       // 2048 chunks of 4
            int row = idx >> 5;
            int c4  = (idx & 31) << 2;
            int grow = node0 + row;
            if (grow < N) {
                const float* sp = sC + row * SC_STRIDE + c4;
                bf16x4 o;
                o[0] = (__bf16)sp[0]; o[1] = (__bf16)sp[1];
                o[2] = (__bf16)sp[2]; o[3] = (__bf16)sp[3];
                *(bf16x4*)(dj + (size_t)grow * DIM + c4) = o;
            }
        }
    }
}

// ---------------------------------------------------------------------------
// Joint CSR build.
// ---------------------------------------------------------------------------
__global__ __launch_bounds__(256) void csr_count_both(const int* __restrict__ a_idx,
                                                      const int* __restrict__ d_idx,
                                                      int* __restrict__ offs,
                                                      int EA, int ED, int N)
{
    int e = blockIdx.x * 256 + threadIdx.x;
    if (e < EA) {
        atomicAdd(&offs[a_idx[3 * (size_t)e + 1]], 1);
    } else if (e < EA + ED) {
        int k = e - EA;
        atomicAdd(&offs[N + d_idx[4 * (size_t)k + 1]], 1);
    }
}

#define SCAN_CHUNK 1024

__global__ __launch_bounds__(256) void scan_s1(int* __restrict__ data,
                                               int* __restrict__ partials, int n)
{
    __shared__ int lds[256];
    const int t = threadIdx.x;
    const int base = blockIdx.x * SCAN_CHUNK + t * 4;
    int v[4];
    #pragma unroll
    for (int i = 0; i < 4; ++i) v[i] = (base + i < n) ? data[base + i] : 0;
    int tsum = v[0] + v[1] + v[2] + v[3];
    lds[t] = tsum; __syncthreads();
    for (int off = 1; off < 256; off <<= 1) {
        int x = (t >= off) ? lds[t - off] : 0;
        __syncthreads();
        lds[t] += x;
        __syncthreads();
    }
    if (t == 255) partials[blockIdx.x] = lds[255];
    int run = lds[t] - tsum;
    #pragma unroll
    for (int i = 0; i < 4; ++i) {
        int nv = run; run += v[i];
        if (base + i < n) data[base + i] = nv;
    }
}

__global__ __launch_bounds__(256) void scan_s2(int* __restrict__ partials, int nb)
{
    __shared__ int lds[256];
    const int t = threadIdx.x;
    int v = (t < nb) ? partials[t] : 0;
    lds[t] = v; __syncthreads();
    for (int off = 1; off < 256; off <<= 1) {
        int x = (t >= off) ? lds[t - off] : 0;
        __syncthreads();
        lds[t] += x;
        __syncthreads();
    }
    if (t < nb) partials[t] = lds[t] - v;
}

__global__ __launch_bounds__(256) void scan_s3(int* __restrict__ data,
                                               const int* __restrict__ partials, int n)
{
    const int add = partials[blockIdx.x];
    const int base = blockIdx.x * SCAN_CHUNK + threadIdx.x * 4;
    #pragma unroll
    for (int i = 0; i < 4; ++i)
        if (base + i < n) data[base + i] += add;
}

__global__ __launch_bounds__(256) void csr_fill_both(const int* __restrict__ a_idx,
                                                     const float* __restrict__ a_val,
                                                     const int* __restrict__ d_idx,
                                                     const float* __restrict__ d_val,
                                                     int* __restrict__ offs,
                                                     int4* __restrict__ recs,
                                                     int EA, int ED, int N)
{
    int e = blockIdx.x * 256 + threadIdx.x;
    if (e < EA) {
        int i0 = a_idx[3 * (size_t)e + 0];
        int i1 = a_idx[3 * (size_t)e + 1];
        int i2 = a_idx[3 * (size_t)e + 2];
        int slot = atomicAdd(&offs[i1], 1);
        recs[slot] = make_int4(i0 * 256, i2 * 256, __float_as_int(a_val[e]), 0);
    } else if (e < EA + ED) {
        int k = e - EA;
        int i0 = d_idx[4 * (size_t)k + 0];
        int i1 = d_idx[4 * (size_t)k + 1];
        int i2 = d_idx[4 * (size_t)k + 2];
        int i3 = d_idx[4 * (size_t)k + 3];
        int slot = atomicAdd(&offs[N + i1], 1);
        recs[slot] = make_int4(i0 * 256, i2 * 256, i3 * 256, __float_as_int(d_val[k]));
    }
}

__device__ __forceinline__ float silu(float x) { return x / (1.f + __expf(-x)); }

// ---------------------------------------------------------------------------
// Gathers: 16-lane node groups, 4 nodes/wave, 8 ch/lane (bf16x8 16B loads).
// Four independent edge chains per wave; serial loop unroll x2 per group
// (R6-proven shape, no guards).
// ---------------------------------------------------------------------------
__global__ __launch_bounds__(256) void gather3(const __bf16* __restrict__ P,
                                               const float* __restrict__ wlast,
                                               const float* __restrict__ bias,
                                               const int* __restrict__ offs,
                                               const int4* __restrict__ recs,
                                               __bf16* __restrict__ agg, int N)
{
    const int tid = threadIdx.x;
    const int n = blockIdx.x * 16 + (tid >> 4);
    if (n >= N) return;
    const int gl = tid & 15;
    const int fb = gl * 16;   // byte offset of this lane's 8 channels
    const size_t NBb = (size_t)N * DIM * 2;
    const char* P0b = (const char*)P;
    const char* P1b = P0b + NBb;
    const char* P2b = P0b + 2 * NBb;
    int start = (n == 0) ? 0 : offs[n - 1];
    int end = offs[n];

    float wl[8], base[8];
    {
        const float* wp = wlast + gl * 8;
        const float* bp = bias + gl * 8;
        bf16x8 p1 = *(const bf16x8*)(P1b + (size_t)n * 256 + fb);
        #pragma unroll
        for (int c = 0; c < 8; ++c) { wl[c] = wp[c]; base[c] = (float)p1[c] + bp[c]; }
    }
    float a[8] = {0.f, 0.f, 0.f, 0.f, 0.f, 0.f, 0.f, 0.f};

    int s = start;
    for (; s + 1 < end; s += 2) {
        int4 rA = recs[s];
        int4 rB = recs[s + 1];
        bf16x8 A0 = *(const bf16x8*)(P0b + rA.x + fb);
        bf16x8 A2 = *(const bf16x8*)(P2b + rA.y + fb);
        bf16x8 B0 = *(const bf16x8*)(P0b + rB.x + fb);
        bf16x8 B2 = *(const bf16x8*)(P2b + rB.y + fb);
        float vA = __int_as_float(rA.z), vB = __int_as_float(rB.z);
        #pragma unroll
        for (int c = 0; c < 8; ++c) {
            a[c] += silu((float)A0[c] + (float)A2[c] + vA * wl[c] + base[c])
                  + silu((float)B0[c] + (float)B2[c] + vB * wl[c] + base[c]);
        }
    }
    if (s < end) {
        int4 rA = recs[s];
        bf16x8 A0 = *(const bf16x8*)(P0b + rA.x + fb);
        bf16x8 A2 = *(const bf16x8*)(P2b + rA.y + fb);
        float vA = __int_as_float(rA.z);
        #pragma unroll
        for (int c = 0; c < 8; ++c)
            a[c] += silu((float)A0[c] + (float)A2[c] + vA * wl[c] + base[c]);
    }
    bf16x8 o;
    #pragma unroll
    for (int c = 0; c < 8; ++c) o[c] = (__bf16)a[c];
    *(bf16x8*)(agg + (size_t)n * DIM + gl * 8) = o;
}

__global__ __launch_bounds__(256) void gather4(const __bf16* __restrict__ P,
                                               const float* __restrict__ wlast,
                                               const float* __restrict__ bias,
                                               const int* __restrict__ offs_d,
                                               const int4* __restrict__ recs,
                                               __bf16* __restrict__ agg, int N)
{
    const int tid = threadIdx.x;
    const int n = blockIdx.x * 16 + (tid >> 4);
    if (n >= N) return;
    const int gl = tid & 15;
    const int fb = gl * 16;
    const size_t NBb = (size_t)N * DIM * 2;
    const char* P0b = (const char*)P;
    const char* P1b = P0b + NBb;
    const char* P2b = P0b + 2 * NBb;
    const char* P3b = P0b + 3 * NBb;
    int start = offs_d[n - 1];  // n==0 -> offs[N-1] == EA == dihedral base
    int end = offs_d[n];

    float wl[8], base[8];
    {
        const float* wp = wlast + gl * 8;
        const float* bp = bias + gl * 8;
        bf16x8 p1 = *(const bf16x8*)(P1b + (size_t)n * 256 + fb);
        #pragma unroll
        for (int c = 0; c < 8; ++c) { wl[c] = wp[c]; base[c] = (float)p1[c] + bp[c]; }
    }
    float a[8] = {0.f, 0.f, 0.f, 0.f, 0.f, 0.f, 0.f, 0.f};

    int s = start;
    for (; s + 1 < end; s += 2) {
        int4 rA = recs[s];
        int4 rB = recs[s + 1];
        bf16x8 A0 = *(const bf16x8*)(P0b + rA.x + fb);
        bf16x8 A2 = *(const bf16x8*)(P2b + rA.y + fb);
        bf16x8 A3 = *(const bf16x8*)(P3b + rA.z + fb);
        bf16x8 B0 = *(const bf16x8*)(P0b + rB.x + fb);
        bf16x8 B2 = *(const bf16x8*)(P2b + rB.y + fb);
        bf16x8 B3 = *(const bf16x8*)(P3b + rB.z + fb);
        float vA = __int_as_float(rA.w), vB = __int_as_float(rB.w);
        #pragma unroll
        for (int c = 0; c < 8; ++c) {
            a[c] += silu((float)A0[c] + (float)A2[c] + (float)A3[c] + vA * wl[c] + base[c])
                  + silu((float)B0[c] + (float)B2[c] + (float)B3[c] + vB * wl[c] + base[c]);
        }
    }
    if (s < end) {
        int4 rA = recs[s];
        bf16x8 A0 = *(const bf16x8*)(P0b + rA.x + fb);
        bf16x8 A2 = *(const bf16x8*)(P2b + rA.y + fb);
        bf16x8 A3 = *(const bf16x8*)(P3b + rA.z + fb);
        float vA = __int_as_float(rA.w);
        #pragma unroll
        for (int c = 0; c < 8; ++c)
            a[c] += silu((float)A0[c] + (float)A2[c] + (float)A3[c] + vA * wl[c] + base[c]);
    }
    bf16x8 o;
    #pragma unroll
    for (int c = 0; c < 8; ++c) o[c] = (__bf16)a[c];
    *(bf16x8*)(agg + (size_t)n * DIM + gl * 8) = o;
}

// ---------------------------------------------------------------------------
// update: out = resid + (bh?bh:0) + (srcf?srcf@Wt[0]:0) + srcb@Wt[last]
// 64-row tiles. Epilogue repacks acc through LDS; resid+bias folded into the
// coalesced float4 phase. resid may == out (same-thread RMW).
// ---------------------------------------------------------------------------
__global__ __launch_bounds__(256, 4) void update_gemm(const float* __restrict__ srcf,
                                                      const __bf16* __restrict__ srcb,
                                                      const __bf16* __restrict__ Wt,
                                                      const float* __restrict__ bh,
                                                      const float* resid,
                                                      float* out, int nsrc, int N)
{
    __shared__ __bf16 sB[128][LDS_STRIDE];
    float* sC = reinterpret_cast<float*>(sB);
    const int tid = threadIdx.x;
    const int node0 = blockIdx.x * 64;
    const int wave = tid >> 6, lane = tid & 63;
    const int lrow = lane & 15;
    const int lk   = (lane >> 4) * 8;
    const int arow = node0 + wave * 16 + lrow;

    f32x4 acc[8];
    #pragma unroll
    for (int ct = 0; ct < 8; ++ct) acc[ct] = (f32x4){0.f, 0.f, 0.f, 0.f};

    for (int s = 0; s < nsrc; ++s) {
        __syncthreads();
        stage_wt(Wt + (size_t)s * 16384, sB, tid);

        bf16x8 afrag[4];
        if (nsrc == 2 && s == 0) load_afrag_f32(srcf, arow, lk, N, afrag);
        else                     load_afrag_bf16(srcb, arow, lk, N, afrag);
        __syncthreads();

        #pragma unroll
        for (int ks = 0; ks < 4; ++ks) {
            int k0 = ks * 32 + lk;
            #pragma unroll
            for (int ct = 0; ct < 8; ++ct) {
                bf16x8 b = *(const bf16x8*)&sB[ct * 16 + lrow][k0];
                acc[ct] = __builtin_amdgcn_mfma_f32_16x16x32_bf16(afrag[ks], b, acc[ct], 0, 0, 0);
            }
        }
    }

    __syncthreads();  // done reading sB -> reuse as sC
    {
        int rbase = wave * 16 + (lane >> 4) * 4;
        #pragma unroll
        for (int r = 0; r < 4; ++r)
            #pragma unroll
            for (int ct = 0; ct < 8; ++ct)
                sC[(rbase + r) * SC_STRIDE + ct * 16 + lrow] = acc[ct][r];
    }
    __syncthreads();

    for (int it = 0; it < 8; ++it) {
        int idx = tid + it * 256;
        int row = idx >> 5;
        int c4  = (idx & 31) << 2;
        int grow = node0 + row;
        if (grow < N) {
            const float* sp = sC + row * SC_STRIDE + c4;
            float4 rv = *(const float4*)(resid + (size_t)grow * DIM + c4);
            float4 bv = bh ? *(const float4*)(bh + c4) : make_float4(0.f, 0.f, 0.f, 0.f);
            float4 ov;
            ov.x = rv.x + bv.x + sp[0];
            ov.y = rv.y + bv.y + sp[1];
            ov.z = rv.z + bv.z + sp[2];
            ov.w = rv.w + bv.w + sp[3];
            *(float4*)(out + (size_t)grow * DIM + c4) = ov;
        }
    }
}

// ---------------------------------------------------------------------------
// ws layout (~145.4 MB; 153.6 MB proven in R2):
//   P: 4*NB bf16 (102.4 MB)  agg: NB bf16 (25.6 MB)
//   offs: 2N int   partials: 256 int   recs: (EA+ED) int4 (16 MB)   Wt: 0.33 MB
// ---------------------------------------------------------------------------
static inline size_t align16(size_t x) { return (x + 15) & ~(size_t)15; }

extern "C" void kernel_launch(void* const* d_in, const int* in_sizes, int n_in,
                              void* d_out, int out_size, void* d_ws, size_t ws_size,
                              hipStream_t stream)
{
    const float* h     = (const float*)d_in[0];
    const int*   a_idx = (const int*)d_in[1];
    const float* a_val = (const float*)d_in[2];
    const int*   d_idx = (const int*)d_in[3];
    const float* d_val = (const float*)d_in[4];
    const float* W_a   = (const float*)d_in[5];
    const float* b_a   = (const float*)d_in[6];
    const float* W_d   = (const float*)d_in[7];
    const float* b_d   = (const float*)d_in[8];
    const float* W_h   = (const float*)d_in[9];
    const float* b_h   = (const float*)d_in[10];
    float* out = (float*)d_out;

    const int N  = in_sizes[0] / DIM;   // 100000
    const int EA = in_sizes[2];         // 500000
    const int ED = in_sizes[4];         // 500000
    const size_t NB = (size_t)N * DIM;
    const int twoN = 2 * N;
    const int NBLK = (twoN + SCAN_CHUNK - 1) / SCAN_CHUNK;  // 196 <= 256

    size_t off = 0;
    __bf16* P   = (__bf16*)((char*)d_ws + off); off = align16(off + 4 * NB * sizeof(__bf16));
    __bf16* agg = (__bf16*)((char*)d_ws + off); off = align16(off + NB * sizeof(__bf16));
    int* offs     = (int*)((char*)d_ws + off);  off = align16(off + (size_t)twoN * sizeof(int));
    int* partials = (int*)((char*)d_ws + off);  off = align16(off + 256 * sizeof(int));
    int4* recs    = (int4*)((char*)d_ws + off); off = align16(off + (size_t)(EA + ED) * sizeof(int4));
    __bf16* Wt  = (__bf16*)((char*)d_ws + off); off = align16(off + (size_t)10 * 16384 * sizeof(__bf16));
    if (ws_size < off) return;  // diagnostic guard

    const int NT64 = (N + 63) / 64;        // 1563
    const int GE = (EA + ED + 255) / 256;
    const int GN16 = (N + 15) / 16;        // 6250

    prep_w<<<(10 * 16384 + 255) / 256, 256, 0, stream>>>(W_a, W_d, W_h, Wt);

    hipMemsetAsync(offs, 0, (size_t)twoN * sizeof(int), stream);
    csr_count_both<<<GE, 256, 0, stream>>>(a_idx, d_idx, offs, EA, ED, N);
    scan_s1<<<NBLK, 256, 0, stream>>>(offs, partials, twoN);
    scan_s2<<<1, 256, 0, stream>>>(partials, NBLK);
    scan_s3<<<NBLK, 256, 0, stream>>>(offs, partials, twoN);
    csr_fill_both<<<GE, 256, 0, stream>>>(a_idx, a_val, d_idx, d_val, offs, recs, EA, ED, N);

    // ---- angle path: Wt blocks 0..2 ----
    proj<<<NT64, 256, 0, stream>>>(h, Wt, P, 3, N);
    gather3<<<GN16, 256, 0, stream>>>(P, W_a + 384 * DIM, b_a, offs, recs, agg, N);
    update_gemm<<<NT64, 256, 0, stream>>>(h, agg, Wt + (size_t)7 * 16384, b_h, h, out, 2, N);

    // ---- dihedral path: Wt blocks 3..6 ----
    proj<<<NT64, 256, 0, stream>>>(h, Wt + (size_t)3 * 16384, P, 4, N);
    gather4<<<GN16, 256, 0, stream>>>(P, W_d + 512 * DIM, b_d, offs + N, recs, agg, N);
    update_gemm<<<NT64, 256, 0, stream>>>(nullptr, agg, Wt + (size_t)9 * 16384, nullptr, out, out, 1, N);
}